// Round 5
// baseline (363.349 us; speedup 1.0000x reference)
//
#include <hip/hip_runtime.h>
#include <hip/hip_bf16.h>
#include <math.h>

// ---------------------------------------------------------------------------
// MultiHeadAttention: out = softmax(mask((X_q Wq^T)(X_k Wk^T)^T / sqrt(valid))) (X_k Wv^T)
// N=4, Lq=Lk=2048, D=1024, H=16, DH=64.  f32 in/out, bf16 MFMA compute inside.
// ---------------------------------------------------------------------------

#define N_S 4
#define LQ 2048
#define LK 2048
#define DM 1024
#define NHEAD 16
#define DHEAD 64

typedef __attribute__((ext_vector_type(8))) short short8;   // 8 bf16 (4 VGPRs)
typedef __attribute__((ext_vector_type(4))) float f32x4;    // 4 fp32

typedef const __attribute__((address_space(1))) void* gptr_t;
typedef __attribute__((address_space(3))) void* lptr_t;

#define GLOAD_LDS(g, l) \
    __builtin_amdgcn_global_load_lds((gptr_t)(const void*)(g), (lptr_t)(void*)(l), 16, 0, 0)

// HW pack via HIP intrinsic (extract via memcpy; __hip_bfloat162 isn't
// trivially copyable so no bit_cast)
static __device__ __forceinline__ unsigned int pkbf(float a, float b) {
    __hip_bfloat162 h = __float22bfloat162_rn(make_float2(a, b));
    unsigned int u;
    __builtin_memcpy(&u, &h, 4);
    return u;
}

static __device__ __forceinline__ f32x4 zero4() {
    f32x4 v; v[0] = 0.f; v[1] = 0.f; v[2] = 0.f; v[3] = 0.f; return v;
}

// ---------------------------------------------------------------------------
// meta body (shared by standalone kernel and fused prep kernel)
// ---------------------------------------------------------------------------
static __device__ __forceinline__ void meta_body(const void* __restrict__ pm,
                                                 int* __restrict__ valid_out,
                                                 float* __restrict__ scale_out) {
    __shared__ int okInt, hasPair, okF32;
    __shared__ int counts[4];
    int t = threadIdx.x;
    if (t == 0) { okInt = 1; hasPair = 0; okF32 = 1; }
    if (t < 4) counts[t] = 0;
    __syncthreads();

    const unsigned int* w = (const unsigned int*)pm;
    int bad_int = 0, pair = 0, bad_f32 = 0;
    for (int i = t; i < 2048; i += 256) {
        unsigned int v = w[i];
        if (v > 1u) bad_int = 1;
        if (v == 0x3F803F80u) pair = 1;
        if (v != 0u && v != 0x3F800000u) bad_f32 = 1;
    }
    if (bad_int) okInt = 0;
    if (pair)    hasPair = 1;
    if (bad_f32) okF32 = 0;
    __syncthreads();

    int mode = okInt ? 0 : (hasPair ? 1 : (okF32 ? 2 : 3)); // 0=i32 1=bf16 2=f32 3=u8
    for (int n = 0; n < 4; n++) {
        int cnt = 0;
        for (int j = t; j < LK; j += 256) {
            int idx = n * LK + j;
            bool z;
            if (mode == 0)      z = (((const int*)pm)[idx] == 0);
            else if (mode == 1) z = (((const unsigned short*)pm)[idx] == 0);
            else if (mode == 2) z = (w[idx] == 0u);
            else                z = (((const unsigned char*)pm)[idx] == 0);
            cnt += z ? 1 : 0;
        }
        atomicAdd(&counts[n], cnt);
    }
    __syncthreads();
    if (t < 4) {
        int c = counts[t] > 0 ? counts[t] : 1;
        valid_out[t] = c;
        scale_out[t] = 1.0f / sqrtf((float)c);
    }
}

__global__ void meta_kernel(const void* __restrict__ pm,
                            int* __restrict__ valid_out,
                            float* __restrict__ scale_out) {
    meta_body(pm, valid_out, scale_out);
}

// ---------------------------------------------------------------------------
// f32 -> bf16 bulk convert, 16 el/thread.
// ---------------------------------------------------------------------------
static __device__ __forceinline__ void conv16(const float* src,
                                              unsigned short* dst, size_t idx) {
    f32x4 a0 = *(const f32x4*)(src + idx);
    f32x4 a1 = *(const f32x4*)(src + idx + 4);
    f32x4 a2 = *(const f32x4*)(src + idx + 8);
    f32x4 a3 = *(const f32x4*)(src + idx + 12);
    uint4 u0, u1;
    u0.x = pkbf(a0[0], a0[1]); u0.y = pkbf(a0[2], a0[3]);
    u0.z = pkbf(a1[0], a1[1]); u0.w = pkbf(a1[2], a1[3]);
    u1.x = pkbf(a2[0], a2[1]); u1.y = pkbf(a2[2], a2[3]);
    u1.z = pkbf(a3[0], a3[1]); u1.w = pkbf(a3[2], a3[3]);
    *(uint4*)(void*)(dst + idx) = u0;
    *(uint4*)(void*)(dst + idx + 8) = u1;
}

__global__ __launch_bounds__(256) void convw_kernel(
    const float* __restrict__ Wq, const float* __restrict__ Wk,
    const float* __restrict__ Wv,
    unsigned short* __restrict__ Wqb, unsigned short* __restrict__ Wkb,
    unsigned short* __restrict__ Wvb)
{
    int z = blockIdx.y;
    const float* src = (z == 0) ? Wq : ((z == 1) ? Wk : Wv);
    unsigned short* dst = (z == 0) ? Wqb : ((z == 1) ? Wkb : Wvb);
    conv16(src, dst, ((size_t)blockIdx.x * 256 + threadIdx.x) * 16);
}

__global__ __launch_bounds__(256) void convx_kernel(
    const float* __restrict__ src, unsigned short* __restrict__ dst)
{
    conv16(src, dst, ((size_t)blockIdx.x * 256 + threadIdx.x) * 16);
}

// ---------------------------------------------------------------------------
// Fused prep (full-ws tier): meta + convw + convx2 in ONE dispatch.
//   block 0         : meta
//   blocks 1..768   : convw (256 blocks per z)
//   blocks 769..4864: convx2 (2048 per tensor)
// ---------------------------------------------------------------------------
__global__ __launch_bounds__(256) void prep_kernel(
    const void* __restrict__ pm, int* __restrict__ valid_out,
    float* __restrict__ scale_out,
    const float* __restrict__ Wq, const float* __restrict__ Wk,
    const float* __restrict__ Wv,
    unsigned short* __restrict__ Wqb, unsigned short* __restrict__ Wkb,
    unsigned short* __restrict__ Wvb,
    const float* __restrict__ xq, const float* __restrict__ xk,
    unsigned short* __restrict__ dq, unsigned short* __restrict__ dk)
{
    int b = blockIdx.x;
    int t = threadIdx.x;
    if (b == 0) {
        meta_body(pm, valid_out, scale_out);
    } else if (b <= 768) {
        int bb = b - 1;
        int z = bb >> 8;
        const float* src = (z == 0) ? Wq : ((z == 1) ? Wk : Wv);
        unsigned short* dst = (z == 0) ? Wqb : ((z == 1) ? Wkb : Wvb);
        conv16(src, dst, ((size_t)(bb & 255) * 256 + t) * 16);
    } else {
        int bb = b - 769;
        const float* src = (bb >= 2048) ? xk : xq;
        unsigned short* dst = (bb >= 2048) ? dk : dq;
        int x = (bb >= 2048) ? bb - 2048 : bb;
        conv16(src, dst, ((size_t)x * 256 + t) * 16);
    }
}

// ---------------------------------------------------------------------------
// Projection body (m97 structure): C = X @ W^T, 128x128 tile, BK=32,
// both operands staged via global_load_lds(16B), XOR group swizzle.
// z<2 (Q,K): A=W, B=X -> lane holds 4 consecutive features -> b64 stores.
//   z==0 pre-scales Q by scal[n]*log2e.
// z==2 (V): A=X, B=W -> 4 consecutive tokens -> b64 stores into Vt (N,D,Lk).
// Early-exit: K/V blocks whose whole 128-token range is >= 64*ceil(valid/64)
// are never read by attn (it reads tokens < 64*tvalid) -> skip, no NaN risk.
// ---------------------------------------------------------------------------
static __device__ __forceinline__ void proj_body(
    const unsigned short* __restrict__ XbQ, const unsigned short* __restrict__ XbK,
    const unsigned short* __restrict__ Wqb, const unsigned short* __restrict__ Wkb,
    const unsigned short* __restrict__ Wvb,
    const float* __restrict__ scal, const int* __restrict__ valid_arr,
    unsigned short* __restrict__ Qb, unsigned short* __restrict__ Kb,
    unsigned short* __restrict__ Vt, int bxi, int byi, int z)
{
    int m0 = bxi << 7, n0 = byi << 7;
    if (z >= 1) {
        int n = m0 >> 11, ml = m0 & 2047;
        int tv64 = ((valid_arr[n] + 63) >> 6) << 6;
        if (ml >= tv64) return;       // block-uniform: tokens never read by attn
    }

    const unsigned short* W = (z == 0) ? Wqb : ((z == 1) ? Wkb : Wvb);
    const unsigned short* Xb = (z == 0) ? XbQ : XbK;

    __shared__ unsigned short Xls[128 * 32];
    __shared__ unsigned short Wls[128 * 32];

    int t = threadIdx.x;
    int wave = t >> 6, lane = t & 63;
    int l15 = lane & 15, quad = lane >> 4;
    int wa = wave >> 1, wb = wave & 1;

    // staging: thread t -> row=t>>2, slot g=t&3 holds col-group g^(row&3)
    int srow = t >> 2;
    int sg = ((t & 3) ^ (srow & 3)) << 3;
    const unsigned short* gX0 = Xb + (size_t)(m0 + srow) * DM + sg;
    const unsigned short* gX1 = Xb + (size_t)(m0 + 64 + srow) * DM + sg;
    const unsigned short* gW0 = W + (size_t)(n0 + srow) * DM + sg;
    const unsigned short* gW1 = W + (size_t)(n0 + 64 + srow) * DM + sg;

    f32x4 acc[4][4];
    #pragma unroll
    for (int i = 0; i < 4; i++)
        #pragma unroll
        for (int j = 0; j < 4; j++) acc[i][j] = zero4();

    int aoff = ((quad ^ (l15 & 3)) << 3);
    const unsigned short* Abuf = (z < 2) ? Wls : Xls;
    const unsigned short* Bbuf = (z < 2) ? Xls : Wls;

    for (int kk = 0; kk < DM; kk += 32) {
        __syncthreads();
        GLOAD_LDS(gX0 + kk, Xls + wave * 512);
        GLOAD_LDS(gX1 + kk, Xls + 2048 + wave * 512);
        GLOAD_LDS(gW0 + kk, Wls + wave * 512);
        GLOAD_LDS(gW1 + kk, Wls + 2048 + wave * 512);
        __syncthreads();

        short8 af[4], bf[4];
        #pragma unroll
        for (int ai = 0; ai < 4; ai++)
            af[ai] = *(const short8*)(const void*)(
                Abuf + ((wa * 64 + ai * 16 + l15) << 5) + aoff);
        #pragma unroll
        for (int bi = 0; bi < 4; bi++)
            bf[bi] = *(const short8*)(const void*)(
                Bbuf + ((wb * 64 + bi * 16 + l15) << 5) + aoff);
        #pragma unroll
        for (int ai = 0; ai < 4; ai++)
            #pragma unroll
            for (int bi = 0; bi < 4; bi++)
                acc[ai][bi] = __builtin_amdgcn_mfma_f32_16x16x32_bf16(
                    af[ai], bf[bi], acc[ai][bi], 0, 0, 0);
    }

    if (z < 2) {
        unsigned short* O = (z == 0) ? Qb : Kb;
        #pragma unroll
        for (int bi = 0; bi < 4; bi++) {
            int token = m0 + wb * 64 + bi * 16 + l15;
            float qs = 1.0f;
            if (z == 0) qs = scal[token >> 11] * 1.44269504f;
            #pragma unroll
            for (int ai = 0; ai < 4; ai++) {
                int feat = n0 + wa * 64 + ai * 16 + quad * 4;
                float v0 = acc[ai][bi][0], v1 = acc[ai][bi][1];
                float v2 = acc[ai][bi][2], v3 = acc[ai][bi][3];
                if (z == 0) { v0 *= qs; v1 *= qs; v2 *= qs; v3 *= qs; }
                uint2 u;
                u.x = pkbf(v0, v1);
                u.y = pkbf(v2, v3);
                *(uint2*)(void*)(O + (size_t)token * DM + feat) = u;
            }
        }
    } else {
        #pragma unroll
        for (int ai = 0; ai < 4; ai++) {
            int token0 = m0 + wa * 64 + ai * 16 + quad * 4;
            int n = token0 >> 11, tl = token0 & 2047;
            #pragma unroll
            for (int bi = 0; bi < 4; bi++) {
                int feat = n0 + wb * 64 + bi * 16 + l15;
                uint2 u;
                u.x = pkbf(acc[ai][bi][0], acc[ai][bi][1]);
                u.y = pkbf(acc[ai][bi][2], acc[ai][bi][3]);
                *(uint2*)(void*)(Vt + ((size_t)n * DM + feat) * LK + tl) = u;
            }
        }
    }
}

// 3D-grid version (phased tier)
__global__ __launch_bounds__(256) void proj_bf16_kernel(
    const unsigned short* __restrict__ XbQ, const unsigned short* __restrict__ XbK,
    const unsigned short* __restrict__ Wqb, const unsigned short* __restrict__ Wkb,
    const unsigned short* __restrict__ Wvb,
    const float* __restrict__ scal, const int* __restrict__ valid_arr,
    unsigned short* __restrict__ Qb, unsigned short* __restrict__ Kb,
    unsigned short* __restrict__ Vt, int zbase)
{
    proj_body(XbQ, XbK, Wqb, Wkb, Wvb, scal, valid_arr, Qb, Kb, Vt,
              blockIdx.x, blockIdx.y, blockIdx.z + zbase);
}

// 1D-grid XCD-swizzled version (full tier, 1536 blocks).
// Mapping: the 8 y-blocks that share one X A-panel (one (x,z) group) land on
// ONE XCD; each XCD owns 24 consecutive (x,z) groups. Per-XCD working set =
// W panels + streaming X panels, L2-friendly.
__global__ __launch_bounds__(256) void proj_bf16_swz_kernel(
    const unsigned short* __restrict__ XbQ, const unsigned short* __restrict__ XbK,
    const unsigned short* __restrict__ Wqb, const unsigned short* __restrict__ Wkb,
    const unsigned short* __restrict__ Wvb,
    const float* __restrict__ scal, const int* __restrict__ valid_arr,
    unsigned short* __restrict__ Qb, unsigned short* __restrict__ Kb,
    unsigned short* __restrict__ Vt)
{
    int id = blockIdx.x;               // 0..1535
    int s = id >> 3;                   // 0..191
    int g = (id & 7) * 24 + (s >> 3);  // (x,z) group, 0..191
    int y = s & 7;
    int z = g >> 6, x = g & 63;
    proj_body(XbQ, XbK, Wqb, Wkb, Wvb, scal, valid_arr, Qb, Kb, Vt, x, y, z);
}

// ---------------------------------------------------------------------------
// Projection fallback (f32 X staged via VGPR cvt) — used when ws too small
// for the bf16-X path.
// ---------------------------------------------------------------------------
__global__ __launch_bounds__(256) void proj_f32_kernel(
    const float* __restrict__ Xq, const float* __restrict__ Xk,
    const unsigned short* __restrict__ Wqb, const unsigned short* __restrict__ Wkb,
    const unsigned short* __restrict__ Wvb,
    const float* __restrict__ scal,
    unsigned short* __restrict__ Qb, unsigned short* __restrict__ Kb,
    unsigned short* __restrict__ Vt)
{
    int z = blockIdx.z;
    const float* X = (z == 0) ? Xq : Xk;
    const unsigned short* W = (z == 0) ? Wqb : ((z == 1) ? Wkb : Wvb);

    __shared__ unsigned short Xls[128 * 32];
    __shared__ unsigned short Wls[128 * 32];

    int t = threadIdx.x;
    int wave = t >> 6, lane = t & 63;
    int l15 = lane & 15, quad = lane >> 4;
    int wa = wave >> 1, wb = wave & 1;
    int m0 = blockIdx.x << 7, n0 = blockIdx.y << 7;

    int arow = t >> 1, ah = t & 1;
    int ag0 = ((2 * ah)     ^ (arow & 3)) << 3;
    int ag1 = ((2 * ah + 1) ^ (arow & 3)) << 3;
    const float* gX = X + (size_t)(m0 + arow) * DM;
    unsigned short* lX = Xls + arow * 32 + ah * 16;

    int brow = t >> 2;
    int bg = ((t & 3) ^ (brow & 3)) << 3;
    const unsigned short* gW0 = W + (size_t)(n0 + brow) * DM + bg;
    const unsigned short* gW1 = W + (size_t)(n0 + 64 + brow) * DM + bg;

    f32x4 acc[4][4];
    #pragma unroll
    for (int i = 0; i < 4; i++)
        #pragma unroll
        for (int j = 0; j < 4; j++) acc[i][j] = zero4();

    int aoff = ((quad ^ (l15 & 3)) << 3);

    f32x4 an0 = *(const f32x4*)(gX + ag0);
    f32x4 an1 = *(const f32x4*)(gX + ag0 + 4);
    f32x4 an2 = *(const f32x4*)(gX + ag1);
    f32x4 an3 = *(const f32x4*)(gX + ag1 + 4);

    const unsigned short* Abuf = (z < 2) ? Wls : Xls;
    const unsigned short* Bbuf = (z < 2) ? Xls : Wls;

    for (int kk = 0; kk < DM; kk += 32) {
        __syncthreads();
        GLOAD_LDS(gW0 + kk, Wls + wave * 512);
        GLOAD_LDS(gW1 + kk, Wls + 2048 + wave * 512);
        uint4 ua, ub;
        ua.x = pkbf(an0[0], an0[1]); ua.y = pkbf(an0[2], an0[3]);
        ua.z = pkbf(an1[0], an1[1]); ua.w = pkbf(an1[2], an1[3]);
        ub.x = pkbf(an2[0], an2[1]); ub.y = pkbf(an2[2], an2[3]);
        ub.z = pkbf(an3[0], an3[1]); ub.w = pkbf(an3[2], an3[3]);
        *(uint4*)(void*)(lX)     = ua;
        *(uint4*)(void*)(lX + 8) = ub;
        __syncthreads();

        if (kk + 32 < DM) {
            an0 = *(const f32x4*)(gX + kk + 32 + ag0);
            an1 = *(const f32x4*)(gX + kk + 32 + ag0 + 4);
            an2 = *(const f32x4*)(gX + kk + 32 + ag1);
            an3 = *(const f32x4*)(gX + kk + 32 + ag1 + 4);
        }

        short8 af[4], bf[4];
        #pragma unroll
        for (int ai = 0; ai < 4; ai++)
            af[ai] = *(const short8*)(const void*)(
                Abuf + ((wa * 64 + ai * 16 + l15) << 5) + aoff);
        #pragma unroll
        for (int bi = 0; bi < 4; bi++)
            bf[bi] = *(const short8*)(const void*)(
                Bbuf + ((wb * 64 + bi * 16 + l15) << 5) + aoff);
        #pragma unroll
        for (int ai = 0; ai < 4; ai++)
            #pragma unroll
            for (int bi = 0; bi < 4; bi++)
                acc[ai][bi] = __builtin_amdgcn_mfma_f32_16x16x32_bf16(
                    af[ai], bf[bi], acc[ai][bi], 0, 0, 0);
    }

    if (z < 2) {
        unsigned short* O = (z == 0) ? Qb : Kb;
        #pragma unroll
        for (int bi = 0; bi < 4; bi++) {
            int token = m0 + wb * 64 + bi * 16 + l15;
            float qs = 1.0f;
            if (z == 0) qs = scal[token >> 11] * 1.44269504f;
            #pragma unroll
            for (int ai = 0; ai < 4; ai++) {
                int feat = n0 + wa * 64 + ai * 16 + quad * 4;
                float v0 = acc[ai][bi][0], v1 = acc[ai][bi][1];
                float v2 = acc[ai][bi][2], v3 = acc[ai][bi][3];
                if (z == 0) { v0 *= qs; v1 *= qs; v2 *= qs; v3 *= qs; }
                uint2 u;
                u.x = pkbf(v0, v1);
                u.y = pkbf(v2, v3);
                *(uint2*)(void*)(O + (size_t)token * DM + feat) = u;
            }
        }
    } else {
        #pragma unroll
        for (int ai = 0; ai < 4; ai++) {
            int token0 = m0 + wa * 64 + ai * 16 + quad * 4;
            int n = token0 >> 11, tl = token0 & 2047;
            #pragma unroll
            for (int bi = 0; bi < 4; bi++) {
                int feat = n0 + wb * 64 + bi * 16 + l15;
                uint2 u;
                u.x = pkbf(acc[ai][bi][0], acc[ai][bi][1]);
                u.y = pkbf(acc[ai][bi][2], acc[ai][bi][3]);
                *(uint2*)(void*)(Vt + ((size_t)n * DM + feat) * LK + tl) = u;
            }
        }
    }
}

// ---------------------------------------------------------------------------
// Flash attention, MAX-FREE + in-register P (permlane) + depth-2 K pipeline.
//
// Round-5 restructure (parallelism, G1):
//   - ONE 64-row Q strip per block (was 2) -> 2048 blocks of 4 waves. Fewer
//     VGPRs/block (~80), same 24KB LDS -> deeper per-CU block queue; doubles
//     schedulable wave supply against the latency chain that rounds 2-4
//     proved immovable by scheduling alone (all pipes <40%, occ 19%).
//   - Balanced XCD swizzle: xcd = id&7; each XCD gets heads {2x,2x+1} of ALL
//     four samples -> per-XCD work identical (fixes round-4's n-grouped
//     imbalance) while keeping per-XCD K/V working set = 8 x 512KB = 4MB
//     (FETCH stays ~22MB, the round-4 L2 win).
//   - Longest strips dispatch FIRST within each XCD (t = 31 - (slot&31)):
//     the tail is short strips, not long ones.
// ---------------------------------------------------------------------------
__global__ __launch_bounds__(256) void attn_kernel(
    const unsigned short* __restrict__ Qb, const unsigned short* __restrict__ Kb,
    const unsigned short* __restrict__ Vt,
    const int* __restrict__ valid_arr,
    float* __restrict__ out)
{
    __shared__ unsigned short Kls[3][64 * 64];

    int id = blockIdx.x;               // 0..2047
    int xcd = id & 7;
    int slot = id >> 3;                // 0..255
    int g = slot >> 5;                 // 0..7: nh-group within this XCD
    int tQ = 31 - (slot & 31);         // Q strip; longest first
    int n = g >> 1;                    // all 4 samples on every XCD
    int h = 2 * xcd + (g & 1);

    int valid = valid_arr[n];
    int tvalid = (valid + 63) >> 6;
    int Tl = (tQ + 1 < tvalid) ? tQ + 1 : tvalid;

    int t = threadIdx.x;
    int wave = t >> 6, lane = t & 63;
    int l15 = lane & 15, quad = lane >> 4;

    int qy = tQ * 64 + wave * 16 + l15;
    int qw0 = tQ * 64 + wave * 16;

    const unsigned short* Qrow = Qb + ((size_t)n * LQ + qy) * DM + h * DHEAD;
    short8 qf0 = *(const short8*)(const void*)(Qrow + quad * 8);
    short8 qf1 = *(const short8*)(const void*)(Qrow + 32 + quad * 8);

    f32x4 O[4];
    #pragma unroll
    for (int i = 0; i < 4; i++) O[i] = zero4();
    f32x4 Lc = zero4();                 // row sums l (per query row)

    short8 onesf;
    #pragma unroll
    for (int i = 0; i < 8; i++) onesf[i] = (short)0x3F80;   // bf16 1.0

    const unsigned short* Kbase = Kb + (size_t)n * LK * DM + h * DHEAD;
    const unsigned short* Vbase = Vt + ((size_t)n * DM + h * DHEAD) * LK;

    int srow0 = t >> 3;
    int sgk   = (((t & 7) ^ (srow0 & 7)) << 3);

    // prologue: issue K(0) -> buf0 and K(1) -> buf1 (depth-2 pipeline)
    GLOAD_LDS(Kbase + (size_t)srow0 * DM + sgk,        &Kls[0][0] + wave * 512);
    GLOAD_LDS(Kbase + (size_t)(32 + srow0) * DM + sgk, &Kls[0][0] + 2048 + wave * 512);
    if (Tl > 1) {
        GLOAD_LDS(Kbase + (size_t)(64 + srow0) * DM + sgk,
                  &Kls[1][0] + wave * 512);
        GLOAD_LDS(Kbase + (size_t)(96 + srow0) * DM + sgk,
                  &Kls[1][0] + 2048 + wave * 512);
        asm volatile("s_waitcnt vmcnt(2)" ::: "memory");   // K(0) landed
    } else {
        asm volatile("s_waitcnt vmcnt(0)" ::: "memory");
    }

    int cur = 0;
    for (int kt = 0; kt < Tl; kt++) {
        int jb = kt << 6;
        int nxt = (cur == 0) ? 2 : cur - 1;   // (kt+2) % 3

        __builtin_amdgcn_sched_barrier(0);
        __builtin_amdgcn_s_barrier();          // raw: no vmcnt drain
        __builtin_amdgcn_sched_barrier(0);

        // V fragments FIRST (oldest in vmcnt queue; hidden under QK + softmax)
        short8 vf0[4], vf1[4];
        #pragma unroll
        for (int cb = 0; cb < 4; cb++) {
            vf0[cb] = *(const short8*)(const void*)(
                Vbase + (size_t)(cb * 16 + l15) * LK + jb + quad * 8);
            vf1[cb] = *(const short8*)(const void*)(
                Vbase + (size_t)(cb * 16 + l15) * LK + jb + 32 + quad * 8);
        }

        // S^T = K Q^T (Q pre-scaled by s*log2e)
        f32x4 s[4];
        __builtin_amdgcn_s_setprio(1);
        #pragma unroll
        for (int cb = 0; cb < 4; cb++) {
            const unsigned short* krow = &Kls[cur][0] + ((cb * 16 + l15) << 6);
            short8 kf0 = *(const short8*)(const void*)(krow + ((quad ^ (l15 & 7)) << 3));
            short8 kf1 = *(const short8*)(const void*)(krow + (((4 + quad) ^ (l15 & 7)) << 3));
            f32x4 sv = zero4();
            sv = __builtin_amdgcn_mfma_f32_16x16x32_bf16(kf0, qf0, sv, 0, 0, 0);
            sv = __builtin_amdgcn_mfma_f32_16x16x32_bf16(kf1, qf1, sv, 0, 0, 0);
            s[cb] = sv;
        }
        __builtin_amdgcn_s_setprio(0);

        // K(kt+2) prefetch (youngest — stays in flight across next barrier)
        if (kt + 2 < Tl) {
            int jb2 = jb + 128;
            GLOAD_LDS(Kbase + (size_t)(jb2 + srow0) * DM + sgk,
                      &Kls[nxt][0] + wave * 512);
            GLOAD_LDS(Kbase + (size_t)(jb2 + 32 + srow0) * DM + sgk,
                      &Kls[nxt][0] + 2048 + wave * 512);
        }

        // ---- mask (boundary tiles only), exp2, pack, permlane ----
        if (jb + 63 > qw0 || jb + 64 > valid) {
            #pragma unroll
            for (int cb = 0; cb < 4; cb++) {
                int jb2 = jb + cb * 16 + quad * 4;
                #pragma unroll
                for (int r = 0; r < 4; r++) {
                    int j = jb2 + r;
                    if (j > qy || j >= valid) s[cb][r] = -1e30f;
                }
            }
        }
        short8 pf0, pf1;
        {
            unsigned int lo[4], hi[4];
            #pragma unroll
            for (int cb = 0; cb < 4; cb++) {
                lo[cb] = pkbf(__builtin_amdgcn_exp2f(s[cb][0]),
                              __builtin_amdgcn_exp2f(s[cb][1]));
                hi[cb] = pkbf(__builtin_amdgcn_exp2f(s[cb][2]),
                              __builtin_amdgcn_exp2f(s[cb][3]));
            }
            asm("v_permlane32_swap_b32 %0, %1" : "+v"(lo[0]), "+v"(lo[1]));
            asm("v_permlane32_swap_b32 %0, %1" : "+v"(hi[0]), "+v"(hi[1]));
            asm("v_permlane32_swap_b32 %0, %1" : "+v"(lo[2]), "+v"(lo[3]));
            asm("v_permlane32_swap_b32 %0, %1" : "+v"(hi[2]), "+v"(hi[3]));
            asm("v_permlane16_swap_b32 %0, %1" : "+v"(lo[0]), "+v"(lo[1]));
            asm("v_permlane16_swap_b32 %0, %1" : "+v"(hi[0]), "+v"(hi[1]));
            asm("v_permlane16_swap_b32 %0, %1" : "+v"(lo[2]), "+v"(lo[3]));
            asm("v_permlane16_swap_b32 %0, %1" : "+v"(hi[2]), "+v"(hi[3]));
            uint4 w0, w1;
            w0.x = lo[0]; w0.y = hi[0]; w0.z = lo[1]; w0.w = hi[1];
            w1.x = lo[2]; w1.y = hi[2]; w1.z = lo[3]; w1.w = hi[3];
            __builtin_memcpy(&pf0, &w0, 16);
            __builtin_memcpy(&pf1, &w1, 16);
        }

        // O += P V and l += P·1
        __builtin_amdgcn_s_setprio(1);
        #pragma unroll
        for (int cb = 0; cb < 4; cb++) {
            O[cb] = __builtin_amdgcn_mfma_f32_16x16x32_bf16(pf0, vf0[cb], O[cb], 0, 0, 0);
            O[cb] = __builtin_amdgcn_mfma_f32_16x16x32_bf16(pf1, vf1[cb], O[cb], 0, 0, 0);
        }
        Lc = __builtin_amdgcn_mfma_f32_16x16x32_bf16(pf0, onesf, Lc, 0, 0, 0);
        Lc = __builtin_amdgcn_mfma_f32_16x16x32_bf16(pf1, onesf, Lc, 0, 0, 0);
        __builtin_amdgcn_s_setprio(0);

        cur = (cur == 2) ? 0 : cur + 1;
    }

    // epilogue (f32): L rows align with O rows (query = quad*4+r) — no shfl.
    float* obase = out + ((size_t)n * LQ) * DM + h * DHEAD;
    #pragma unroll
    for (int r = 0; r < 4; r++) {
        float iL = 1.0f / Lc[r];
        int row = tQ * 64 + wave * 16 + quad * 4 + r;
        #pragma unroll
        for (int cb = 0; cb < 4; cb++) {
            obase[(size_t)row * DM + cb * 16 + l15] = O[cb][r] * iL;
        }
    }
}

// ---------------------------------------------------------------------------
extern "C" void kernel_launch(void* const* d_in, const int* in_sizes, int n_in,
                              void* d_out, int out_size, void* d_ws, size_t ws_size,
                              hipStream_t stream)
{
    (void)in_sizes; (void)n_in; (void)out_size;

    const float* query = (const float*)d_in[0];
    const float* key   = (const float*)d_in[1];
    const float* Wq    = (const float*)d_in[2];
    const float* Wk    = (const float*)d_in[3];
    const float* Wv    = (const float*)d_in[4];
    const void* pmask  = d_in[6];

    char* ws = (char*)d_ws;
    unsigned short* Qb  = (unsigned short*)(ws);                              // 16 MB
    unsigned short* Kb  = (unsigned short*)(ws + (size_t)16 * 1024 * 1024);   // 16 MB
    unsigned short* Vt  = (unsigned short*)(ws + (size_t)32 * 1024 * 1024);   // 16 MB
    int*   valid = (int*)  (ws + (size_t)48 * 1024 * 1024);
    float* scal  = (float*)(ws + (size_t)48 * 1024 * 1024 + 64);
    unsigned short* Wqb = (unsigned short*)(ws + (size_t)48 * 1024 * 1024 + 4096);
    unsigned short* Wkb = Wqb + (size_t)DM * DM;
    unsigned short* Wvb = Wkb + (size_t)DM * DM;
    unsigned short* XbQ = Wvb + (size_t)DM * DM;     // 16 MB
    unsigned short* XbK = XbQ + (size_t)N_S * LQ * DM;   // 16 MB (full tier only)

    size_t xbytes      = (size_t)N_S * LQ * DM * 2;
    size_t need_phased = (size_t)(48 * 1024 * 1024) + 4096
                       + 3 * (size_t)DM * DM * 2 + xbytes;
    size_t need_full   = need_phased + xbytes;

    if (ws_size >= need_full) {
        // full tier: ONE prep dispatch (meta + convw + convx2), one fused
        // XCD-swizzled projection dispatch, one attention dispatch.
        prep_kernel<<<dim3(1 + 768 + 4096), 256, 0, stream>>>(
            pmask, valid, scal, Wq, Wk, Wv, Wqb, Wkb, Wvb,
            query, key, XbQ, XbK);
        proj_bf16_swz_kernel<<<dim3(1536), 256, 0, stream>>>(
            XbQ, XbK, Wqb, Wkb, Wvb, scal, valid, Qb, Kb, Vt);
    } else if (ws_size >= need_phased) {
        // phased tier: one Xb buffer, reused.
        meta_kernel<<<1, 256, 0, stream>>>(pmask, valid, scal);
        convw_kernel<<<dim3(256, 3), 256, 0, stream>>>(Wq, Wk, Wv, Wqb, Wkb, Wvb);
        convx_kernel<<<2048, 256, 0, stream>>>(query, XbQ);
        proj_bf16_kernel<<<dim3(64, 8, 1), 256, 0, stream>>>(
            XbQ, XbQ, Wqb, Wkb, Wvb, scal, valid, Qb, Kb, Vt, 0);
        convx_kernel<<<2048, 256, 0, stream>>>(key, XbQ);
        proj_bf16_kernel<<<dim3(64, 8, 2), 256, 0, stream>>>(
            XbQ, XbQ, Wqb, Wkb, Wvb, scal, valid, Qb, Kb, Vt, 1);
    } else {
        meta_kernel<<<1, 256, 0, stream>>>(pmask, valid, scal);
        convw_kernel<<<dim3(256, 3), 256, 0, stream>>>(Wq, Wk, Wv, Wqb, Wkb, Wvb);
        proj_f32_kernel<<<dim3(64, 8, 3), 256, 0, stream>>>(
            query, key, Wqb, Wkb, Wvb, scal, Qb, Kb, Vt);
    }

    attn_kernel<<<dim3(2048), 256, 0, stream>>>(Qb, Kb, Vt, valid,
                                                (float*)d_out);
}

// Round 6
// 343.621 us; speedup vs baseline: 1.0574x; 1.0574x over previous
//
#include <hip/hip_runtime.h>
#include <hip/hip_bf16.h>
#include <math.h>

// ---------------------------------------------------------------------------
// MultiHeadAttention: out = softmax(mask((X_q Wq^T)(X_k Wk^T)^T / sqrt(valid))) (X_k Wv^T)
// N=4, Lq=Lk=2048, D=1024, H=16, DH=64.  f32 in/out, bf16 MFMA compute inside.
// ---------------------------------------------------------------------------

#define N_S 4
#define LQ 2048
#define LK 2048
#define DM 1024
#define NHEAD 16
#define DHEAD 64

typedef __attribute__((ext_vector_type(8))) short short8;   // 8 bf16 (4 VGPRs)
typedef __attribute__((ext_vector_type(4))) float f32x4;    // 4 fp32

typedef const __attribute__((address_space(1))) void* gptr_t;
typedef __attribute__((address_space(3))) void* lptr_t;

#define GLOAD_LDS(g, l) \
    __builtin_amdgcn_global_load_lds((gptr_t)(const void*)(g), (lptr_t)(void*)(l), 16, 0, 0)

// HW pack via HIP intrinsic (extract via memcpy; __hip_bfloat162 isn't
// trivially copyable so no bit_cast)
static __device__ __forceinline__ unsigned int pkbf(float a, float b) {
    __hip_bfloat162 h = __float22bfloat162_rn(make_float2(a, b));
    unsigned int u;
    __builtin_memcpy(&u, &h, 4);
    return u;
}

static __device__ __forceinline__ f32x4 zero4() {
    f32x4 v; v[0] = 0.f; v[1] = 0.f; v[2] = 0.f; v[3] = 0.f; return v;
}

// ---------------------------------------------------------------------------
// meta body (shared by standalone kernel and fused prep kernel)
// ---------------------------------------------------------------------------
static __device__ __forceinline__ void meta_body(const void* __restrict__ pm,
                                                 int* __restrict__ valid_out,
                                                 float* __restrict__ scale_out) {
    __shared__ int okInt, hasPair, okF32;
    __shared__ int counts[4];
    int t = threadIdx.x;
    if (t == 0) { okInt = 1; hasPair = 0; okF32 = 1; }
    if (t < 4) counts[t] = 0;
    __syncthreads();

    const unsigned int* w = (const unsigned int*)pm;
    int bad_int = 0, pair = 0, bad_f32 = 0;
    for (int i = t; i < 2048; i += 256) {
        unsigned int v = w[i];
        if (v > 1u) bad_int = 1;
        if (v == 0x3F803F80u) pair = 1;
        if (v != 0u && v != 0x3F800000u) bad_f32 = 1;
    }
    if (bad_int) okInt = 0;
    if (pair)    hasPair = 1;
    if (bad_f32) okF32 = 0;
    __syncthreads();

    int mode = okInt ? 0 : (hasPair ? 1 : (okF32 ? 2 : 3)); // 0=i32 1=bf16 2=f32 3=u8
    for (int n = 0; n < 4; n++) {
        int cnt = 0;
        for (int j = t; j < LK; j += 256) {
            int idx = n * LK + j;
            bool z;
            if (mode == 0)      z = (((const int*)pm)[idx] == 0);
            else if (mode == 1) z = (((const unsigned short*)pm)[idx] == 0);
            else if (mode == 2) z = (w[idx] == 0u);
            else                z = (((const unsigned char*)pm)[idx] == 0);
            cnt += z ? 1 : 0;
        }
        atomicAdd(&counts[n], cnt);
    }
    __syncthreads();
    if (t < 4) {
        int c = counts[t] > 0 ? counts[t] : 1;
        valid_out[t] = c;
        scale_out[t] = 1.0f / sqrtf((float)c);
    }
}

__global__ void meta_kernel(const void* __restrict__ pm,
                            int* __restrict__ valid_out,
                            float* __restrict__ scale_out) {
    meta_body(pm, valid_out, scale_out);
}

// ---------------------------------------------------------------------------
// f32 -> bf16 bulk convert, 16 el/thread.
// ---------------------------------------------------------------------------
static __device__ __forceinline__ void conv16(const float* src,
                                              unsigned short* dst, size_t idx) {
    f32x4 a0 = *(const f32x4*)(src + idx);
    f32x4 a1 = *(const f32x4*)(src + idx + 4);
    f32x4 a2 = *(const f32x4*)(src + idx + 8);
    f32x4 a3 = *(const f32x4*)(src + idx + 12);
    uint4 u0, u1;
    u0.x = pkbf(a0[0], a0[1]); u0.y = pkbf(a0[2], a0[3]);
    u0.z = pkbf(a1[0], a1[1]); u0.w = pkbf(a1[2], a1[3]);
    u1.x = pkbf(a2[0], a2[1]); u1.y = pkbf(a2[2], a2[3]);
    u1.z = pkbf(a3[0], a3[1]); u1.w = pkbf(a3[2], a3[3]);
    *(uint4*)(void*)(dst + idx) = u0;
    *(uint4*)(void*)(dst + idx + 8) = u1;
}

__global__ __launch_bounds__(256) void convw_kernel(
    const float* __restrict__ Wq, const float* __restrict__ Wk,
    const float* __restrict__ Wv,
    unsigned short* __restrict__ Wqb, unsigned short* __restrict__ Wkb,
    unsigned short* __restrict__ Wvb)
{
    int z = blockIdx.y;
    const float* src = (z == 0) ? Wq : ((z == 1) ? Wk : Wv);
    unsigned short* dst = (z == 0) ? Wqb : ((z == 1) ? Wkb : Wvb);
    conv16(src, dst, ((size_t)blockIdx.x * 256 + threadIdx.x) * 16);
}

__global__ __launch_bounds__(256) void convx_kernel(
    const float* __restrict__ src, unsigned short* __restrict__ dst)
{
    conv16(src, dst, ((size_t)blockIdx.x * 256 + threadIdx.x) * 16);
}

// ---------------------------------------------------------------------------
// Fused prep (full-ws tier): meta + convw + convx2 in ONE dispatch.
//   block 0         : meta
//   blocks 1..768   : convw (256 blocks per z)
//   blocks 769..4864: convx2 (2048 per tensor)
// ---------------------------------------------------------------------------
__global__ __launch_bounds__(256) void prep_kernel(
    const void* __restrict__ pm, int* __restrict__ valid_out,
    float* __restrict__ scale_out,
    const float* __restrict__ Wq, const float* __restrict__ Wk,
    const float* __restrict__ Wv,
    unsigned short* __restrict__ Wqb, unsigned short* __restrict__ Wkb,
    unsigned short* __restrict__ Wvb,
    const float* __restrict__ xq, const float* __restrict__ xk,
    unsigned short* __restrict__ dq, unsigned short* __restrict__ dk)
{
    int b = blockIdx.x;
    int t = threadIdx.x;
    if (b == 0) {
        meta_body(pm, valid_out, scale_out);
    } else if (b <= 768) {
        int bb = b - 1;
        int z = bb >> 8;
        const float* src = (z == 0) ? Wq : ((z == 1) ? Wk : Wv);
        unsigned short* dst = (z == 0) ? Wqb : ((z == 1) ? Wkb : Wvb);
        conv16(src, dst, ((size_t)(bb & 255) * 256 + t) * 16);
    } else {
        int bb = b - 769;
        const float* src = (bb >= 2048) ? xk : xq;
        unsigned short* dst = (bb >= 2048) ? dk : dq;
        int x = (bb >= 2048) ? bb - 2048 : bb;
        conv16(src, dst, ((size_t)x * 256 + t) * 16);
    }
}

// ---------------------------------------------------------------------------
// Projection body (m97 structure): C = X @ W^T, 128x128 tile, BK=32,
// both operands staged via global_load_lds(16B), XOR group swizzle.
// z<2 (Q,K): A=W, B=X -> lane holds 4 consecutive features -> b64 stores.
//   z==0 pre-scales Q by scal[n]*log2e.
// z==2 (V): A=X, B=W -> 4 consecutive tokens -> b64 stores into Vt (N,D,Lk).
// Early-exit: K/V blocks whose whole 128-token range is >= 64*ceil(valid/64)
// are never read by attn (it reads tokens < 64*tvalid) -> skip, no NaN risk.
// ---------------------------------------------------------------------------
static __device__ __forceinline__ void proj_body(
    const unsigned short* __restrict__ XbQ, const unsigned short* __restrict__ XbK,
    const unsigned short* __restrict__ Wqb, const unsigned short* __restrict__ Wkb,
    const unsigned short* __restrict__ Wvb,
    const float* __restrict__ scal, const int* __restrict__ valid_arr,
    unsigned short* __restrict__ Qb, unsigned short* __restrict__ Kb,
    unsigned short* __restrict__ Vt, int bxi, int byi, int z)
{
    int m0 = bxi << 7, n0 = byi << 7;
    if (z >= 1) {
        int n = m0 >> 11, ml = m0 & 2047;
        int tv64 = ((valid_arr[n] + 63) >> 6) << 6;
        if (ml >= tv64) return;       // block-uniform: tokens never read by attn
    }

    const unsigned short* W = (z == 0) ? Wqb : ((z == 1) ? Wkb : Wvb);
    const unsigned short* Xb = (z == 0) ? XbQ : XbK;

    __shared__ unsigned short Xls[128 * 32];
    __shared__ unsigned short Wls[128 * 32];

    int t = threadIdx.x;
    int wave = t >> 6, lane = t & 63;
    int l15 = lane & 15, quad = lane >> 4;
    int wa = wave >> 1, wb = wave & 1;

    // staging: thread t -> row=t>>2, slot g=t&3 holds col-group g^(row&3)
    int srow = t >> 2;
    int sg = ((t & 3) ^ (srow & 3)) << 3;
    const unsigned short* gX0 = Xb + (size_t)(m0 + srow) * DM + sg;
    const unsigned short* gX1 = Xb + (size_t)(m0 + 64 + srow) * DM + sg;
    const unsigned short* gW0 = W + (size_t)(n0 + srow) * DM + sg;
    const unsigned short* gW1 = W + (size_t)(n0 + 64 + srow) * DM + sg;

    f32x4 acc[4][4];
    #pragma unroll
    for (int i = 0; i < 4; i++)
        #pragma unroll
        for (int j = 0; j < 4; j++) acc[i][j] = zero4();

    int aoff = ((quad ^ (l15 & 3)) << 3);
    const unsigned short* Abuf = (z < 2) ? Wls : Xls;
    const unsigned short* Bbuf = (z < 2) ? Xls : Wls;

    for (int kk = 0; kk < DM; kk += 32) {
        __syncthreads();
        GLOAD_LDS(gX0 + kk, Xls + wave * 512);
        GLOAD_LDS(gX1 + kk, Xls + 2048 + wave * 512);
        GLOAD_LDS(gW0 + kk, Wls + wave * 512);
        GLOAD_LDS(gW1 + kk, Wls + 2048 + wave * 512);
        __syncthreads();

        short8 af[4], bf[4];
        #pragma unroll
        for (int ai = 0; ai < 4; ai++)
            af[ai] = *(const short8*)(const void*)(
                Abuf + ((wa * 64 + ai * 16 + l15) << 5) + aoff);
        #pragma unroll
        for (int bi = 0; bi < 4; bi++)
            bf[bi] = *(const short8*)(const void*)(
                Bbuf + ((wb * 64 + bi * 16 + l15) << 5) + aoff);
        #pragma unroll
        for (int ai = 0; ai < 4; ai++)
            #pragma unroll
            for (int bi = 0; bi < 4; bi++)
                acc[ai][bi] = __builtin_amdgcn_mfma_f32_16x16x32_bf16(
                    af[ai], bf[bi], acc[ai][bi], 0, 0, 0);
    }

    if (z < 2) {
        unsigned short* O = (z == 0) ? Qb : Kb;
        #pragma unroll
        for (int bi = 0; bi < 4; bi++) {
            int token = m0 + wb * 64 + bi * 16 + l15;
            float qs = 1.0f;
            if (z == 0) qs = scal[token >> 11] * 1.44269504f;
            #pragma unroll
            for (int ai = 0; ai < 4; ai++) {
                int feat = n0 + wa * 64 + ai * 16 + quad * 4;
                float v0 = acc[ai][bi][0], v1 = acc[ai][bi][1];
                float v2 = acc[ai][bi][2], v3 = acc[ai][bi][3];
                if (z == 0) { v0 *= qs; v1 *= qs; v2 *= qs; v3 *= qs; }
                uint2 u;
                u.x = pkbf(v0, v1);
                u.y = pkbf(v2, v3);
                *(uint2*)(void*)(O + (size_t)token * DM + feat) = u;
            }
        }
    } else {
        #pragma unroll
        for (int ai = 0; ai < 4; ai++) {
            int token0 = m0 + wa * 64 + ai * 16 + quad * 4;
            int n = token0 >> 11, tl = token0 & 2047;
            #pragma unroll
            for (int bi = 0; bi < 4; bi++) {
                int feat = n0 + wb * 64 + bi * 16 + l15;
                uint2 u;
                u.x = pkbf(acc[ai][bi][0], acc[ai][bi][1]);
                u.y = pkbf(acc[ai][bi][2], acc[ai][bi][3]);
                *(uint2*)(void*)(Vt + ((size_t)n * DM + feat) * LK + tl) = u;
            }
        }
    }
}

// 3D-grid version (phased tier)
__global__ __launch_bounds__(256) void proj_bf16_kernel(
    const unsigned short* __restrict__ XbQ, const unsigned short* __restrict__ XbK,
    const unsigned short* __restrict__ Wqb, const unsigned short* __restrict__ Wkb,
    const unsigned short* __restrict__ Wvb,
    const float* __restrict__ scal, const int* __restrict__ valid_arr,
    unsigned short* __restrict__ Qb, unsigned short* __restrict__ Kb,
    unsigned short* __restrict__ Vt, int zbase)
{
    proj_body(XbQ, XbK, Wqb, Wkb, Wvb, scal, valid_arr, Qb, Kb, Vt,
              blockIdx.x, blockIdx.y, blockIdx.z + zbase);
}

// 1D-grid XCD-swizzled version (full tier, 1536 blocks).
__global__ __launch_bounds__(256) void proj_bf16_swz_kernel(
    const unsigned short* __restrict__ XbQ, const unsigned short* __restrict__ XbK,
    const unsigned short* __restrict__ Wqb, const unsigned short* __restrict__ Wkb,
    const unsigned short* __restrict__ Wvb,
    const float* __restrict__ scal, const int* __restrict__ valid_arr,
    unsigned short* __restrict__ Qb, unsigned short* __restrict__ Kb,
    unsigned short* __restrict__ Vt)
{
    int id = blockIdx.x;               // 0..1535
    int s = id >> 3;                   // 0..191
    int g = (id & 7) * 24 + (s >> 3);  // (x,z) group, 0..191
    int y = s & 7;
    int z = g >> 6, x = g & 63;
    proj_body(XbQ, XbK, Wqb, Wkb, Wvb, scal, valid_arr, Qb, Kb, Vt, x, y, z);
}

// ---------------------------------------------------------------------------
// Projection fallback (f32 X staged via VGPR cvt) — used when ws too small
// for the bf16-X path.
// ---------------------------------------------------------------------------
__global__ __launch_bounds__(256) void proj_f32_kernel(
    const float* __restrict__ Xq, const float* __restrict__ Xk,
    const unsigned short* __restrict__ Wqb, const unsigned short* __restrict__ Wkb,
    const unsigned short* __restrict__ Wvb,
    const float* __restrict__ scal,
    unsigned short* __restrict__ Qb, unsigned short* __restrict__ Kb,
    unsigned short* __restrict__ Vt)
{
    int z = blockIdx.z;
    const float* X = (z == 0) ? Xq : Xk;
    const unsigned short* W = (z == 0) ? Wqb : ((z == 1) ? Wkb : Wvb);

    __shared__ unsigned short Xls[128 * 32];
    __shared__ unsigned short Wls[128 * 32];

    int t = threadIdx.x;
    int wave = t >> 6, lane = t & 63;
    int l15 = lane & 15, quad = lane >> 4;
    int wa = wave >> 1, wb = wave & 1;
    int m0 = blockIdx.x << 7, n0 = blockIdx.y << 7;

    int arow = t >> 1, ah = t & 1;
    int ag0 = ((2 * ah)     ^ (arow & 3)) << 3;
    int ag1 = ((2 * ah + 1) ^ (arow & 3)) << 3;
    const float* gX = X + (size_t)(m0 + arow) * DM;
    unsigned short* lX = Xls + arow * 32 + ah * 16;

    int brow = t >> 2;
    int bg = ((t & 3) ^ (brow & 3)) << 3;
    const unsigned short* gW0 = W + (size_t)(n0 + brow) * DM + bg;
    const unsigned short* gW1 = W + (size_t)(n0 + 64 + brow) * DM + bg;

    f32x4 acc[4][4];
    #pragma unroll
    for (int i = 0; i < 4; i++)
        #pragma unroll
        for (int j = 0; j < 4; j++) acc[i][j] = zero4();

    int aoff = ((quad ^ (l15 & 3)) << 3);

    f32x4 an0 = *(const f32x4*)(gX + ag0);
    f32x4 an1 = *(const f32x4*)(gX + ag0 + 4);
    f32x4 an2 = *(const f32x4*)(gX + ag1);
    f32x4 an3 = *(const f32x4*)(gX + ag1 + 4);

    const unsigned short* Abuf = (z < 2) ? Wls : Xls;
    const unsigned short* Bbuf = (z < 2) ? Xls : Wls;

    for (int kk = 0; kk < DM; kk += 32) {
        __syncthreads();
        GLOAD_LDS(gW0 + kk, Wls + wave * 512);
        GLOAD_LDS(gW1 + kk, Wls + 2048 + wave * 512);
        uint4 ua, ub;
        ua.x = pkbf(an0[0], an0[1]); ua.y = pkbf(an0[2], an0[3]);
        ua.z = pkbf(an1[0], an1[1]); ua.w = pkbf(an1[2], an1[3]);
        ub.x = pkbf(an2[0], an2[1]); ub.y = pkbf(an2[2], an2[3]);
        ub.z = pkbf(an3[0], an3[1]); ub.w = pkbf(an3[2], an3[3]);
        *(uint4*)(void*)(lX)     = ua;
        *(uint4*)(void*)(lX + 8) = ub;
        __syncthreads();

        if (kk + 32 < DM) {
            an0 = *(const f32x4*)(gX + kk + 32 + ag0);
            an1 = *(const f32x4*)(gX + kk + 32 + ag0 + 4);
            an2 = *(const f32x4*)(gX + kk + 32 + ag1);
            an3 = *(const f32x4*)(gX + kk + 32 + ag1 + 4);
        }

        short8 af[4], bf[4];
        #pragma unroll
        for (int ai = 0; ai < 4; ai++)
            af[ai] = *(const short8*)(const void*)(
                Abuf + ((wa * 64 + ai * 16 + l15) << 5) + aoff);
        #pragma unroll
        for (int bi = 0; bi < 4; bi++)
            bf[bi] = *(const short8*)(const void*)(
                Bbuf + ((wb * 64 + bi * 16 + l15) << 5) + aoff);
        #pragma unroll
        for (int ai = 0; ai < 4; ai++)
            #pragma unroll
            for (int bi = 0; bi < 4; bi++)
                acc[ai][bi] = __builtin_amdgcn_mfma_f32_16x16x32_bf16(
                    af[ai], bf[bi], acc[ai][bi], 0, 0, 0);
    }

    if (z < 2) {
        unsigned short* O = (z == 0) ? Qb : Kb;
        #pragma unroll
        for (int bi = 0; bi < 4; bi++) {
            int token = m0 + wb * 64 + bi * 16 + l15;
            float qs = 1.0f;
            if (z == 0) qs = scal[token >> 11] * 1.44269504f;
            #pragma unroll
            for (int ai = 0; ai < 4; ai++) {
                int feat = n0 + wa * 64 + ai * 16 + quad * 4;
                float v0 = acc[ai][bi][0], v1 = acc[ai][bi][1];
                float v2 = acc[ai][bi][2], v3 = acc[ai][bi][3];
                if (z == 0) { v0 *= qs; v1 *= qs; v2 *= qs; v3 *= qs; }
                uint2 u;
                u.x = pkbf(v0, v1);
                u.y = pkbf(v2, v3);
                *(uint2*)(void*)(O + (size_t)token * DM + feat) = u;
            }
        }
    } else {
        #pragma unroll
        for (int ai = 0; ai < 4; ai++) {
            int token0 = m0 + wa * 64 + ai * 16 + quad * 4;
            int n = token0 >> 11, tl = token0 & 2047;
            #pragma unroll
            for (int bi = 0; bi < 4; bi++) {
                int feat = n0 + wb * 64 + bi * 16 + l15;
                uint2 u;
                u.x = pkbf(acc[ai][bi][0], acc[ai][bi][1]);
                u.y = pkbf(acc[ai][bi][2], acc[ai][bi][3]);
                *(uint2*)(void*)(Vt + ((size_t)n * DM + feat) * LK + tl) = u;
            }
        }
    }
}

// ---------------------------------------------------------------------------
// Flash attention, MAX-FREE + in-register P (permlane) + depth-2 K pipeline.
//
// Round-6 restructure (iteration-count amortization):
//   r5 proved wall = (total block-iterations/256) x ~2950cy, INDEPENDENT of
//   occupancy and of per-iteration strip work. So: amortize MORE strips under
//   each iteration's fixed cost. 8 waves (512 thr), 4 strips/block
//   {b, 15-b, 16+b, 31-b}; waves 0-3 handle pair (b,15-b), waves 4-7 pair
//   (16+b,31-b). Per-wave work identical to the r0 structure (2 strips,
//   shared V frags). Iterations per nh: sum_b min(32-b,tv) = 228 vs r0's 392.
//   K tile staged once per iter for all 4 strips (1 GLOAD_LDS/wave).
//   Balanced XCD swizzle + longest-first kept (FETCH ~22MB).
//   Safety: waves whose strips finish early issue no V loads, so an explicit
//   end-of-body vmcnt(1) (vmcnt(0) when no prefetch was issued) guarantees
//   every wave's K(kt+1) landed before barrier(kt+1).
// ---------------------------------------------------------------------------
__global__ __launch_bounds__(512) void attn_kernel(
    const unsigned short* __restrict__ Qb, const unsigned short* __restrict__ Kb,
    const unsigned short* __restrict__ Vt,
    const int* __restrict__ valid_arr,
    float* __restrict__ out)
{
    __shared__ unsigned short Kls[3][64 * 64];

    int id = blockIdx.x;               // 0..511
    int xcd = id & 7;
    int slot = id >> 3;                // 0..63
    int g = slot >> 3;                 // 0..7: (n, h-parity) group
    int b = slot & 7;                  // 0..7; b=0 dispatched first (longest)
    int n = g >> 1;
    int h = 2 * xcd + (g & 1);

    int valid = valid_arr[n];
    int tvalid = (valid + 63) >> 6;

    int t = threadIdx.x;
    int wave = t >> 6, lane = t & 63;
    int l15 = lane & 15, quad = lane >> 4;
    int pair = wave >> 2;              // 0..1
    int w4 = wave & 3;                 // 16-row slice within strip

    int tA = pair ? (16 + b) : b;
    int tB = pair ? (31 - b) : (15 - b);
    int TlA = (tA + 1 < tvalid) ? tA + 1 : tvalid;
    int TlB = (tB + 1 < tvalid) ? tB + 1 : tvalid;   // TlB >= TlA for b<=7
    int Tloop = (32 - b < tvalid) ? 32 - b : tvalid; // block-uniform max

    int qyA = tA * 64 + w4 * 16 + l15;
    int qyB = tB * 64 + w4 * 16 + l15;
    int qw0A = tA * 64 + w4 * 16;
    int qw0B = tB * 64 + w4 * 16;

    const unsigned short* QrowA = Qb + ((size_t)n * LQ + qyA) * DM + h * DHEAD;
    const unsigned short* QrowB = Qb + ((size_t)n * LQ + qyB) * DM + h * DHEAD;
    short8 qfA0 = *(const short8*)(const void*)(QrowA + quad * 8);
    short8 qfA1 = *(const short8*)(const void*)(QrowA + 32 + quad * 8);
    short8 qfB0 = *(const short8*)(const void*)(QrowB + quad * 8);
    short8 qfB1 = *(const short8*)(const void*)(QrowB + 32 + quad * 8);

    f32x4 OA[4], OB[4];
    #pragma unroll
    for (int i = 0; i < 4; i++) { OA[i] = zero4(); OB[i] = zero4(); }
    f32x4 LAcc = zero4(), LBcc = zero4();

    short8 onesf;
    #pragma unroll
    for (int i = 0; i < 8; i++) onesf[i] = (short)0x3F80;   // bf16 1.0

    const unsigned short* Kbase = Kb + (size_t)n * LK * DM + h * DHEAD;
    const unsigned short* Vbase = Vt + ((size_t)n * DM + h * DHEAD) * LK;

    // K staging, 512 threads: row = t>>3 (0..63), XOR col-group swizzle on the
    // global source; each wave issues ONE GLOAD (1 KB -> wave*1024 B of tile).
    int srow0 = t >> 3;
    int sgk   = (((t & 7) ^ (srow0 & 7)) << 3);

    // prologue: K(0) -> buf0, K(1) -> buf1 (depth-2)
    GLOAD_LDS(Kbase + (size_t)srow0 * DM + sgk, &Kls[0][0] + wave * 512);
    if (Tloop > 1) {
        GLOAD_LDS(Kbase + (size_t)(64 + srow0) * DM + sgk,
                  &Kls[1][0] + wave * 512);
        asm volatile("s_waitcnt vmcnt(1)" ::: "memory");   // K(0) landed
    } else {
        asm volatile("s_waitcnt vmcnt(0)" ::: "memory");
    }

    int cur = 0;
    for (int kt = 0; kt < Tloop; kt++) {
        int jb = kt << 6;
        bool doB = (kt < TlB);
        bool doA = (kt < TlA);
        bool pf = (kt + 2 < Tloop);
        int nxt = (cur == 0) ? 2 : cur - 1;   // (kt+2) % 3

        __builtin_amdgcn_sched_barrier(0);
        __builtin_amdgcn_s_barrier();          // raw: no vmcnt drain
        __builtin_amdgcn_sched_barrier(0);

        // V fragments FIRST (oldest in vmcnt queue; hidden under QK+softmax)
        short8 vf0[4], vf1[4];
        if (doB) {
            #pragma unroll
            for (int cb = 0; cb < 4; cb++) {
                vf0[cb] = *(const short8*)(const void*)(
                    Vbase + (size_t)(cb * 16 + l15) * LK + jb + quad * 8);
                vf1[cb] = *(const short8*)(const void*)(
                    Vbase + (size_t)(cb * 16 + l15) * LK + jb + 32 + quad * 8);
            }
        }

        // S^T = K Q^T (Q pre-scaled by s*log2e)
        f32x4 sA[4], sB[4];
        if (doB) {
            __builtin_amdgcn_s_setprio(1);
            #pragma unroll
            for (int cb = 0; cb < 4; cb++) {
                const unsigned short* krow = &Kls[cur][0] + ((cb * 16 + l15) << 6);
                short8 kf0 = *(const short8*)(const void*)(krow + ((quad ^ (l15 & 7)) << 3));
                short8 kf1 = *(const short8*)(const void*)(krow + (((4 + quad) ^ (l15 & 7)) << 3));
                f32x4 sb = zero4();
                sb = __builtin_amdgcn_mfma_f32_16x16x32_bf16(kf0, qfB0, sb, 0, 0, 0);
                sb = __builtin_amdgcn_mfma_f32_16x16x32_bf16(kf1, qfB1, sb, 0, 0, 0);
                sB[cb] = sb;
                if (doA) {
                    f32x4 sa = zero4();
                    sa = __builtin_amdgcn_mfma_f32_16x16x32_bf16(kf0, qfA0, sa, 0, 0, 0);
                    sa = __builtin_amdgcn_mfma_f32_16x16x32_bf16(kf1, qfA1, sa, 0, 0, 0);
                    sA[cb] = sa;
                }
            }
            __builtin_amdgcn_s_setprio(0);
        }

        // K(kt+2) prefetch (youngest — in flight across the next barrier)
        if (pf) {
            int jb2 = jb + 128;
            GLOAD_LDS(Kbase + (size_t)(jb2 + srow0) * DM + sgk,
                      &Kls[nxt][0] + wave * 512);
        }

        if (doB) {
            // ---- strip B: mask (boundary only), exp2, pack, permlane ----
            if (jb + 63 > qw0B || jb + 64 > valid) {
                #pragma unroll
                for (int cb = 0; cb < 4; cb++) {
                    int jb2 = jb + cb * 16 + quad * 4;
                    #pragma unroll
                    for (int r = 0; r < 4; r++) {
                        int j = jb2 + r;
                        if (j > qyB || j >= valid) sB[cb][r] = -1e30f;
                    }
                }
            }
            short8 pfB0, pfB1;
            {
                unsigned int lo[4], hi[4];
                #pragma unroll
                for (int cb = 0; cb < 4; cb++) {
                    lo[cb] = pkbf(__builtin_amdgcn_exp2f(sB[cb][0]),
                                  __builtin_amdgcn_exp2f(sB[cb][1]));
                    hi[cb] = pkbf(__builtin_amdgcn_exp2f(sB[cb][2]),
                                  __builtin_amdgcn_exp2f(sB[cb][3]));
                }
                asm("v_permlane32_swap_b32 %0, %1" : "+v"(lo[0]), "+v"(lo[1]));
                asm("v_permlane32_swap_b32 %0, %1" : "+v"(hi[0]), "+v"(hi[1]));
                asm("v_permlane32_swap_b32 %0, %1" : "+v"(lo[2]), "+v"(lo[3]));
                asm("v_permlane32_swap_b32 %0, %1" : "+v"(hi[2]), "+v"(hi[3]));
                asm("v_permlane16_swap_b32 %0, %1" : "+v"(lo[0]), "+v"(lo[1]));
                asm("v_permlane16_swap_b32 %0, %1" : "+v"(hi[0]), "+v"(hi[1]));
                asm("v_permlane16_swap_b32 %0, %1" : "+v"(lo[2]), "+v"(lo[3]));
                asm("v_permlane16_swap_b32 %0, %1" : "+v"(hi[2]), "+v"(hi[3]));
                uint4 w0, w1;
                w0.x = lo[0]; w0.y = hi[0]; w0.z = lo[1]; w0.w = hi[1];
                w1.x = lo[2]; w1.y = hi[2]; w1.z = lo[3]; w1.w = hi[3];
                __builtin_memcpy(&pfB0, &w0, 16);
                __builtin_memcpy(&pfB1, &w1, 16);
            }
            __builtin_amdgcn_s_setprio(1);
            #pragma unroll
            for (int cb = 0; cb < 4; cb++) {
                OB[cb] = __builtin_amdgcn_mfma_f32_16x16x32_bf16(pfB0, vf0[cb], OB[cb], 0, 0, 0);
                OB[cb] = __builtin_amdgcn_mfma_f32_16x16x32_bf16(pfB1, vf1[cb], OB[cb], 0, 0, 0);
            }
            LBcc = __builtin_amdgcn_mfma_f32_16x16x32_bf16(pfB0, onesf, LBcc, 0, 0, 0);
            LBcc = __builtin_amdgcn_mfma_f32_16x16x32_bf16(pfB1, onesf, LBcc, 0, 0, 0);
            __builtin_amdgcn_s_setprio(0);
        }

        if (doA) {
            if (jb + 63 > qw0A || jb + 64 > valid) {
                #pragma unroll
                for (int cb = 0; cb < 4; cb++) {
                    int jb2 = jb + cb * 16 + quad * 4;
                    #pragma unroll
                    for (int r = 0; r < 4; r++) {
                        int j = jb2 + r;
                        if (j > qyA || j >= valid) sA[cb][r] = -1e30f;
                    }
                }
            }
            short8 pfA0, pfA1;
            {
                unsigned int lo[4], hi[4];
                #pragma unroll
                for (int cb = 0; cb < 4; cb++) {
                    lo[cb] = pkbf(__builtin_amdgcn_exp2f(sA[cb][0]),
                                  __builtin_amdgcn_exp2f(sA[cb][1]));
                    hi[cb] = pkbf(__builtin_amdgcn_exp2f(sA[cb][2]),
                                  __builtin_amdgcn_exp2f(sA[cb][3]));
                }
                asm("v_permlane32_swap_b32 %0, %1" : "+v"(lo[0]), "+v"(lo[1]));
                asm("v_permlane32_swap_b32 %0, %1" : "+v"(hi[0]), "+v"(hi[1]));
                asm("v_permlane32_swap_b32 %0, %1" : "+v"(lo[2]), "+v"(lo[3]));
                asm("v_permlane32_swap_b32 %0, %1" : "+v"(hi[2]), "+v"(hi[3]));
                asm("v_permlane16_swap_b32 %0, %1" : "+v"(lo[0]), "+v"(lo[1]));
                asm("v_permlane16_swap_b32 %0, %1" : "+v"(hi[0]), "+v"(hi[1]));
                asm("v_permlane16_swap_b32 %0, %1" : "+v"(lo[2]), "+v"(lo[3]));
                asm("v_permlane16_swap_b32 %0, %1" : "+v"(hi[2]), "+v"(hi[3]));
                uint4 w0, w1;
                w0.x = lo[0]; w0.y = hi[0]; w0.z = lo[1]; w0.w = hi[1];
                w1.x = lo[2]; w1.y = hi[2]; w1.z = lo[3]; w1.w = hi[3];
                __builtin_memcpy(&pfA0, &w0, 16);
                __builtin_memcpy(&pfA1, &w1, 16);
            }
            __builtin_amdgcn_s_setprio(1);
            #pragma unroll
            for (int cb = 0; cb < 4; cb++) {
                OA[cb] = __builtin_amdgcn_mfma_f32_16x16x32_bf16(pfA0, vf0[cb], OA[cb], 0, 0, 0);
                OA[cb] = __builtin_amdgcn_mfma_f32_16x16x32_bf16(pfA1, vf1[cb], OA[cb], 0, 0, 0);
            }
            LAcc = __builtin_amdgcn_mfma_f32_16x16x32_bf16(pfA0, onesf, LAcc, 0, 0, 0);
            LAcc = __builtin_amdgcn_mfma_f32_16x16x32_bf16(pfA1, onesf, LAcc, 0, 0, 0);
            __builtin_amdgcn_s_setprio(0);
        }

        // EVERY wave (incl. strip-inactive) guarantees its K(kt+1) GLOAD has
        // landed before the next barrier; keeps K(kt+2) in flight when issued.
        if (pf) asm volatile("s_waitcnt vmcnt(1)" ::: "memory");
        else    asm volatile("s_waitcnt vmcnt(0)" ::: "memory");

        cur = (cur == 2) ? 0 : cur + 1;
    }

    // epilogue (f32): L rows align with O rows (query = quad*4+r) — no shfl.
    float* obase = out + ((size_t)n * LQ) * DM + h * DHEAD;
    #pragma unroll
    for (int r = 0; r < 4; r++) {
        float iA = 1.0f / LAcc[r];
        float iB = 1.0f / LBcc[r];
        int rowA = tA * 64 + w4 * 16 + quad * 4 + r;
        int rowB = tB * 64 + w4 * 16 + quad * 4 + r;
        #pragma unroll
        for (int cb = 0; cb < 4; cb++) {
            obase[(size_t)rowA * DM + cb * 16 + l15] = OA[cb][r] * iA;
            obase[(size_t)rowB * DM + cb * 16 + l15] = OB[cb][r] * iB;
        }
    }
}

// ---------------------------------------------------------------------------
extern "C" void kernel_launch(void* const* d_in, const int* in_sizes, int n_in,
                              void* d_out, int out_size, void* d_ws, size_t ws_size,
                              hipStream_t stream)
{
    (void)in_sizes; (void)n_in; (void)out_size;

    const float* query = (const float*)d_in[0];
    const float* key   = (const float*)d_in[1];
    const float* Wq    = (const float*)d_in[2];
    const float* Wk    = (const float*)d_in[3];
    const float* Wv    = (const float*)d_in[4];
    const void* pmask  = d_in[6];

    char* ws = (char*)d_ws;
    unsigned short* Qb  = (unsigned short*)(ws);                              // 16 MB
    unsigned short* Kb  = (unsigned short*)(ws + (size_t)16 * 1024 * 1024);   // 16 MB
    unsigned short* Vt  = (unsigned short*)(ws + (size_t)32 * 1024 * 1024);   // 16 MB
    int*   valid = (int*)  (ws + (size_t)48 * 1024 * 1024);
    float* scal  = (float*)(ws + (size_t)48 * 1024 * 1024 + 64);
    unsigned short* Wqb = (unsigned short*)(ws + (size_t)48 * 1024 * 1024 + 4096);
    unsigned short* Wkb = Wqb + (size_t)DM * DM;
    unsigned short* Wvb = Wkb + (size_t)DM * DM;
    unsigned short* XbQ = Wvb + (size_t)DM * DM;     // 16 MB
    unsigned short* XbK = XbQ + (size_t)N_S * LQ * DM;   // 16 MB (full tier only)

    size_t xbytes      = (size_t)N_S * LQ * DM * 2;
    size_t need_phased = (size_t)(48 * 1024 * 1024) + 4096
                       + 3 * (size_t)DM * DM * 2 + xbytes;
    size_t need_full   = need_phased + xbytes;

    if (ws_size >= need_full) {
        // full tier: ONE prep dispatch (meta + convw + convx2), one fused
        // XCD-swizzled projection dispatch, one attention dispatch.
        prep_kernel<<<dim3(1 + 768 + 4096), 256, 0, stream>>>(
            pmask, valid, scal, Wq, Wk, Wv, Wqb, Wkb, Wvb,
            query, key, XbQ, XbK);
        proj_bf16_swz_kernel<<<dim3(1536), 256, 0, stream>>>(
            XbQ, XbK, Wqb, Wkb, Wvb, scal, valid, Qb, Kb, Vt);
    } else if (ws_size >= need_phased) {
        // phased tier: one Xb buffer, reused.
        meta_kernel<<<1, 256, 0, stream>>>(pmask, valid, scal);
        convw_kernel<<<dim3(256, 3), 256, 0, stream>>>(Wq, Wk, Wv, Wqb, Wkb, Wvb);
        convx_kernel<<<2048, 256, 0, stream>>>(query, XbQ);
        proj_bf16_kernel<<<dim3(64, 8, 1), 256, 0, stream>>>(
            XbQ, XbQ, Wqb, Wkb, Wvb, scal, valid, Qb, Kb, Vt, 0);
        convx_kernel<<<2048, 256, 0, stream>>>(key, XbQ);
        proj_bf16_kernel<<<dim3(64, 8, 2), 256, 0, stream>>>(
            XbQ, XbQ, Wqb, Wkb, Wvb, scal, valid, Qb, Kb, Vt, 1);
    } else {
        meta_kernel<<<1, 256, 0, stream>>>(pmask, valid, scal);
        convw_kernel<<<dim3(256, 3), 256, 0, stream>>>(Wq, Wk, Wv, Wqb, Wkb, Wvb);
        proj_f32_kernel<<<dim3(64, 8, 3), 256, 0, stream>>>(
            query, key, Wqb, Wkb, Wvb, scal, Qb, Kb, Vt);
    }

    attn_kernel<<<dim3(512), 512, 0, stream>>>(Qb, Kb, Vt, valid,
                                               (float*)d_out);
}

// Round 7
// 315.372 us; speedup vs baseline: 1.1521x; 1.0896x over previous
//
#include <hip/hip_runtime.h>
#include <hip/hip_bf16.h>
#include <math.h>

// ---------------------------------------------------------------------------
// MultiHeadAttention: out = softmax(mask((X_q Wq^T)(X_k Wk^T)^T / sqrt(valid))) (X_k Wv^T)
// N=4, Lq=Lk=2048, D=1024, H=16, DH=64.  f32 in/out, bf16 MFMA compute inside.
// ---------------------------------------------------------------------------

#define N_S 4
#define LQ 2048
#define LK 2048
#define DM 1024
#define NHEAD 16
#define DHEAD 64

typedef __attribute__((ext_vector_type(8))) short short8;   // 8 bf16 (4 VGPRs)
typedef __attribute__((ext_vector_type(4))) float f32x4;    // 4 fp32

typedef const __attribute__((address_space(1))) void* gptr_t;
typedef __attribute__((address_space(3))) void* lptr_t;

#define GLOAD_LDS(g, l) \
    __builtin_amdgcn_global_load_lds((gptr_t)(const void*)(g), (lptr_t)(void*)(l), 16, 0, 0)

// HW pack via HIP intrinsic (extract via memcpy; __hip_bfloat162 isn't
// trivially copyable so no bit_cast)
static __device__ __forceinline__ unsigned int pkbf(float a, float b) {
    __hip_bfloat162 h = __float22bfloat162_rn(make_float2(a, b));
    unsigned int u;
    __builtin_memcpy(&u, &h, 4);
    return u;
}

static __device__ __forceinline__ f32x4 zero4() {
    f32x4 v; v[0] = 0.f; v[1] = 0.f; v[2] = 0.f; v[3] = 0.f; return v;
}

// ---------------------------------------------------------------------------
// meta body (shared by standalone kernel and fused prep kernel)
// ---------------------------------------------------------------------------
static __device__ __forceinline__ void meta_body(const void* __restrict__ pm,
                                                 int* __restrict__ valid_out,
                                                 float* __restrict__ scale_out) {
    __shared__ int okInt, hasPair, okF32;
    __shared__ int counts[4];
    int t = threadIdx.x;
    if (t == 0) { okInt = 1; hasPair = 0; okF32 = 1; }
    if (t < 4) counts[t] = 0;
    __syncthreads();

    const unsigned int* w = (const unsigned int*)pm;
    int bad_int = 0, pair = 0, bad_f32 = 0;
    for (int i = t; i < 2048; i += 256) {
        unsigned int v = w[i];
        if (v > 1u) bad_int = 1;
        if (v == 0x3F803F80u) pair = 1;
        if (v != 0u && v != 0x3F800000u) bad_f32 = 1;
    }
    if (bad_int) okInt = 0;
    if (pair)    hasPair = 1;
    if (bad_f32) okF32 = 0;
    __syncthreads();

    int mode = okInt ? 0 : (hasPair ? 1 : (okF32 ? 2 : 3)); // 0=i32 1=bf16 2=f32 3=u8
    for (int n = 0; n < 4; n++) {
        int cnt = 0;
        for (int j = t; j < LK; j += 256) {
            int idx = n * LK + j;
            bool z;
            if (mode == 0)      z = (((const int*)pm)[idx] == 0);
            else if (mode == 1) z = (((const unsigned short*)pm)[idx] == 0);
            else if (mode == 2) z = (w[idx] == 0u);
            else                z = (((const unsigned char*)pm)[idx] == 0);
            cnt += z ? 1 : 0;
        }
        atomicAdd(&counts[n], cnt);
    }
    __syncthreads();
    if (t < 4) {
        int c = counts[t] > 0 ? counts[t] : 1;
        valid_out[t] = c;
        scale_out[t] = 1.0f / sqrtf((float)c);
    }
}

__global__ void meta_kernel(const void* __restrict__ pm,
                            int* __restrict__ valid_out,
                            float* __restrict__ scale_out) {
    meta_body(pm, valid_out, scale_out);
}

// ---------------------------------------------------------------------------
// f32 -> bf16 bulk convert, 16 el/thread.
// ---------------------------------------------------------------------------
static __device__ __forceinline__ void conv16(const float* src,
                                              unsigned short* dst, size_t idx) {
    f32x4 a0 = *(const f32x4*)(src + idx);
    f32x4 a1 = *(const f32x4*)(src + idx + 4);
    f32x4 a2 = *(const f32x4*)(src + idx + 8);
    f32x4 a3 = *(const f32x4*)(src + idx + 12);
    uint4 u0, u1;
    u0.x = pkbf(a0[0], a0[1]); u0.y = pkbf(a0[2], a0[3]);
    u0.z = pkbf(a1[0], a1[1]); u0.w = pkbf(a1[2], a1[3]);
    u1.x = pkbf(a2[0], a2[1]); u1.y = pkbf(a2[2], a2[3]);
    u1.z = pkbf(a3[0], a3[1]); u1.w = pkbf(a3[2], a3[3]);
    *(uint4*)(void*)(dst + idx) = u0;
    *(uint4*)(void*)(dst + idx + 8) = u1;
}

__global__ __launch_bounds__(256) void convw_kernel(
    const float* __restrict__ Wq, const float* __restrict__ Wk,
    const float* __restrict__ Wv,
    unsigned short* __restrict__ Wqb, unsigned short* __restrict__ Wkb,
    unsigned short* __restrict__ Wvb)
{
    int z = blockIdx.y;
    const float* src = (z == 0) ? Wq : ((z == 1) ? Wk : Wv);
    unsigned short* dst = (z == 0) ? Wqb : ((z == 1) ? Wkb : Wvb);
    conv16(src, dst, ((size_t)blockIdx.x * 256 + threadIdx.x) * 16);
}

__global__ __launch_bounds__(256) void convx_kernel(
    const float* __restrict__ src, unsigned short* __restrict__ dst)
{
    conv16(src, dst, ((size_t)blockIdx.x * 256 + threadIdx.x) * 16);
}

// ---------------------------------------------------------------------------
// Fused prep (full-ws tier): meta + convw + convx2 in ONE dispatch.
//   block 0         : meta
//   blocks 1..768   : convw (256 blocks per z)
//   blocks 769..4864: convx2 (2048 per tensor)
// ---------------------------------------------------------------------------
__global__ __launch_bounds__(256) void prep_kernel(
    const void* __restrict__ pm, int* __restrict__ valid_out,
    float* __restrict__ scale_out,
    const float* __restrict__ Wq, const float* __restrict__ Wk,
    const float* __restrict__ Wv,
    unsigned short* __restrict__ Wqb, unsigned short* __restrict__ Wkb,
    unsigned short* __restrict__ Wvb,
    const float* __restrict__ xq, const float* __restrict__ xk,
    unsigned short* __restrict__ dq, unsigned short* __restrict__ dk)
{
    int b = blockIdx.x;
    int t = threadIdx.x;
    if (b == 0) {
        meta_body(pm, valid_out, scale_out);
    } else if (b <= 768) {
        int bb = b - 1;
        int z = bb >> 8;
        const float* src = (z == 0) ? Wq : ((z == 1) ? Wk : Wv);
        unsigned short* dst = (z == 0) ? Wqb : ((z == 1) ? Wkb : Wvb);
        conv16(src, dst, ((size_t)(bb & 255) * 256 + t) * 16);
    } else {
        int bb = b - 769;
        const float* src = (bb >= 2048) ? xk : xq;
        unsigned short* dst = (bb >= 2048) ? dk : dq;
        int x = (bb >= 2048) ? bb - 2048 : bb;
        conv16(src, dst, ((size_t)x * 256 + t) * 16);
    }
}

// ---------------------------------------------------------------------------
// Projection body (m97 structure): C = X @ W^T, 128x128 tile, BK=32,
// both operands staged via global_load_lds(16B), XOR group swizzle.
// z<2 (Q,K): A=W, B=X -> lane holds 4 consecutive features -> b64 stores.
//   z==0 pre-scales Q by scal[n]*log2e.
// z==2 (V): A=X, B=W -> 4 consecutive tokens -> b64 stores into Vt (N,D,Lk).
// Early-exit: K/V blocks whose whole 128-token range is >= 64*ceil(valid/64)
// are never read by attn (it reads tokens < 64*tvalid) -> skip, no NaN risk.
// ---------------------------------------------------------------------------
static __device__ __forceinline__ void proj_body(
    const unsigned short* __restrict__ XbQ, const unsigned short* __restrict__ XbK,
    const unsigned short* __restrict__ Wqb, const unsigned short* __restrict__ Wkb,
    const unsigned short* __restrict__ Wvb,
    const float* __restrict__ scal, const int* __restrict__ valid_arr,
    unsigned short* __restrict__ Qb, unsigned short* __restrict__ Kb,
    unsigned short* __restrict__ Vt, int bxi, int byi, int z)
{
    int m0 = bxi << 7, n0 = byi << 7;
    if (z >= 1) {
        int n = m0 >> 11, ml = m0 & 2047;
        int tv64 = ((valid_arr[n] + 63) >> 6) << 6;
        if (ml >= tv64) return;       // block-uniform: tokens never read by attn
    }

    const unsigned short* W = (z == 0) ? Wqb : ((z == 1) ? Wkb : Wvb);
    const unsigned short* Xb = (z == 0) ? XbQ : XbK;

    __shared__ unsigned short Xls[128 * 32];
    __shared__ unsigned short Wls[128 * 32];

    int t = threadIdx.x;
    int wave = t >> 6, lane = t & 63;
    int l15 = lane & 15, quad = lane >> 4;
    int wa = wave >> 1, wb = wave & 1;

    // staging: thread t -> row=t>>2, slot g=t&3 holds col-group g^(row&3)
    int srow = t >> 2;
    int sg = ((t & 3) ^ (srow & 3)) << 3;
    const unsigned short* gX0 = Xb + (size_t)(m0 + srow) * DM + sg;
    const unsigned short* gX1 = Xb + (size_t)(m0 + 64 + srow) * DM + sg;
    const unsigned short* gW0 = W + (size_t)(n0 + srow) * DM + sg;
    const unsigned short* gW1 = W + (size_t)(n0 + 64 + srow) * DM + sg;

    f32x4 acc[4][4];
    #pragma unroll
    for (int i = 0; i < 4; i++)
        #pragma unroll
        for (int j = 0; j < 4; j++) acc[i][j] = zero4();

    int aoff = ((quad ^ (l15 & 3)) << 3);
    const unsigned short* Abuf = (z < 2) ? Wls : Xls;
    const unsigned short* Bbuf = (z < 2) ? Xls : Wls;

    for (int kk = 0; kk < DM; kk += 32) {
        __syncthreads();
        GLOAD_LDS(gX0 + kk, Xls + wave * 512);
        GLOAD_LDS(gX1 + kk, Xls + 2048 + wave * 512);
        GLOAD_LDS(gW0 + kk, Wls + wave * 512);
        GLOAD_LDS(gW1 + kk, Wls + 2048 + wave * 512);
        __syncthreads();

        short8 af[4], bf[4];
        #pragma unroll
        for (int ai = 0; ai < 4; ai++)
            af[ai] = *(const short8*)(const void*)(
                Abuf + ((wa * 64 + ai * 16 + l15) << 5) + aoff);
        #pragma unroll
        for (int bi = 0; bi < 4; bi++)
            bf[bi] = *(const short8*)(const void*)(
                Bbuf + ((wb * 64 + bi * 16 + l15) << 5) + aoff);
        #pragma unroll
        for (int ai = 0; ai < 4; ai++)
            #pragma unroll
            for (int bi = 0; bi < 4; bi++)
                acc[ai][bi] = __builtin_amdgcn_mfma_f32_16x16x32_bf16(
                    af[ai], bf[bi], acc[ai][bi], 0, 0, 0);
    }

    if (z < 2) {
        unsigned short* O = (z == 0) ? Qb : Kb;
        #pragma unroll
        for (int bi = 0; bi < 4; bi++) {
            int token = m0 + wb * 64 + bi * 16 + l15;
            float qs = 1.0f;
            if (z == 0) qs = scal[token >> 11] * 1.44269504f;
            #pragma unroll
            for (int ai = 0; ai < 4; ai++) {
                int feat = n0 + wa * 64 + ai * 16 + quad * 4;
                float v0 = acc[ai][bi][0], v1 = acc[ai][bi][1];
                float v2 = acc[ai][bi][2], v3 = acc[ai][bi][3];
                if (z == 0) { v0 *= qs; v1 *= qs; v2 *= qs; v3 *= qs; }
                uint2 u;
                u.x = pkbf(v0, v1);
                u.y = pkbf(v2, v3);
                *(uint2*)(void*)(O + (size_t)token * DM + feat) = u;
            }
        }
    } else {
        #pragma unroll
        for (int ai = 0; ai < 4; ai++) {
            int token0 = m0 + wa * 64 + ai * 16 + quad * 4;
            int n = token0 >> 11, tl = token0 & 2047;
            #pragma unroll
            for (int bi = 0; bi < 4; bi++) {
                int feat = n0 + wb * 64 + bi * 16 + l15;
                uint2 u;
                u.x = pkbf(acc[ai][bi][0], acc[ai][bi][1]);
                u.y = pkbf(acc[ai][bi][2], acc[ai][bi][3]);
                *(uint2*)(void*)(Vt + ((size_t)n * DM + feat) * LK + tl) = u;
            }
        }
    }
}

// 3D-grid version (phased tier)
__global__ __launch_bounds__(256) void proj_bf16_kernel(
    const unsigned short* __restrict__ XbQ, const unsigned short* __restrict__ XbK,
    const unsigned short* __restrict__ Wqb, const unsigned short* __restrict__ Wkb,
    const unsigned short* __restrict__ Wvb,
    const float* __restrict__ scal, const int* __restrict__ valid_arr,
    unsigned short* __restrict__ Qb, unsigned short* __restrict__ Kb,
    unsigned short* __restrict__ Vt, int zbase)
{
    proj_body(XbQ, XbK, Wqb, Wkb, Wvb, scal, valid_arr, Qb, Kb, Vt,
              blockIdx.x, blockIdx.y, blockIdx.z + zbase);
}

// 1D-grid XCD-swizzled version (full tier, 1536 blocks).
__global__ __launch_bounds__(256) void proj_bf16_swz_kernel(
    const unsigned short* __restrict__ XbQ, const unsigned short* __restrict__ XbK,
    const unsigned short* __restrict__ Wqb, const unsigned short* __restrict__ Wkb,
    const unsigned short* __restrict__ Wvb,
    const float* __restrict__ scal, const int* __restrict__ valid_arr,
    unsigned short* __restrict__ Qb, unsigned short* __restrict__ Kb,
    unsigned short* __restrict__ Vt)
{
    int id = blockIdx.x;               // 0..1535
    int s = id >> 3;                   // 0..191
    int g = (id & 7) * 24 + (s >> 3);  // (x,z) group, 0..191
    int y = s & 7;
    int z = g >> 6, x = g & 63;
    proj_body(XbQ, XbK, Wqb, Wkb, Wvb, scal, valid_arr, Qb, Kb, Vt, x, y, z);
}

// ---------------------------------------------------------------------------
// Projection fallback (f32 X staged via VGPR cvt) — used when ws too small
// for the bf16-X path.
// ---------------------------------------------------------------------------
__global__ __launch_bounds__(256) void proj_f32_kernel(
    const float* __restrict__ Xq, const float* __restrict__ Xk,
    const unsigned short* __restrict__ Wqb, const unsigned short* __restrict__ Wkb,
    const unsigned short* __restrict__ Wvb,
    const float* __restrict__ scal,
    unsigned short* __restrict__ Qb, unsigned short* __restrict__ Kb,
    unsigned short* __restrict__ Vt)
{
    int z = blockIdx.z;
    const float* X = (z == 0) ? Xq : Xk;
    const unsigned short* W = (z == 0) ? Wqb : ((z == 1) ? Wkb : Wvb);

    __shared__ unsigned short Xls[128 * 32];
    __shared__ unsigned short Wls[128 * 32];

    int t = threadIdx.x;
    int wave = t >> 6, lane = t & 63;
    int l15 = lane & 15, quad = lane >> 4;
    int wa = wave >> 1, wb = wave & 1;
    int m0 = blockIdx.x << 7, n0 = blockIdx.y << 7;

    int arow = t >> 1, ah = t & 1;
    int ag0 = ((2 * ah)     ^ (arow & 3)) << 3;
    int ag1 = ((2 * ah + 1) ^ (arow & 3)) << 3;
    const float* gX = X + (size_t)(m0 + arow) * DM;
    unsigned short* lX = Xls + arow * 32 + ah * 16;

    int brow = t >> 2;
    int bg = ((t & 3) ^ (brow & 3)) << 3;
    const unsigned short* gW0 = W + (size_t)(n0 + brow) * DM + bg;
    const unsigned short* gW1 = W + (size_t)(n0 + 64 + brow) * DM + bg;

    f32x4 acc[4][4];
    #pragma unroll
    for (int i = 0; i < 4; i++)
        #pragma unroll
        for (int j = 0; j < 4; j++) acc[i][j] = zero4();

    int aoff = ((quad ^ (l15 & 3)) << 3);

    f32x4 an0 = *(const f32x4*)(gX + ag0);
    f32x4 an1 = *(const f32x4*)(gX + ag0 + 4);
    f32x4 an2 = *(const f32x4*)(gX + ag1);
    f32x4 an3 = *(const f32x4*)(gX + ag1 + 4);

    const unsigned short* Abuf = (z < 2) ? Wls : Xls;
    const unsigned short* Bbuf = (z < 2) ? Xls : Wls;

    for (int kk = 0; kk < DM; kk += 32) {
        __syncthreads();
        GLOAD_LDS(gW0 + kk, Wls + wave * 512);
        GLOAD_LDS(gW1 + kk, Wls + 2048 + wave * 512);
        uint4 ua, ub;
        ua.x = pkbf(an0[0], an0[1]); ua.y = pkbf(an0[2], an0[3]);
        ua.z = pkbf(an1[0], an1[1]); ua.w = pkbf(an1[2], an1[3]);
        ub.x = pkbf(an2[0], an2[1]); ub.y = pkbf(an2[2], an2[3]);
        ub.z = pkbf(an3[0], an3[1]); ub.w = pkbf(an3[2], an3[3]);
        *(uint4*)(void*)(lX)     = ua;
        *(uint4*)(void*)(lX + 8) = ub;
        __syncthreads();

        if (kk + 32 < DM) {
            an0 = *(const f32x4*)(gX + kk + 32 + ag0);
            an1 = *(const f32x4*)(gX + kk + 32 + ag0 + 4);
            an2 = *(const f32x4*)(gX + kk + 32 + ag1);
            an3 = *(const f32x4*)(gX + kk + 32 + ag1 + 4);
        }

        short8 af[4], bf[4];
        #pragma unroll
        for (int ai = 0; ai < 4; ai++)
            af[ai] = *(const short8*)(const void*)(
                Abuf + ((wa * 64 + ai * 16 + l15) << 5) + aoff);
        #pragma unroll
        for (int bi = 0; bi < 4; bi++)
            bf[bi] = *(const short8*)(const void*)(
                Bbuf + ((wb * 64 + bi * 16 + l15) << 5) + aoff);
        #pragma unroll
        for (int ai = 0; ai < 4; ai++)
            #pragma unroll
            for (int bi = 0; bi < 4; bi++)
                acc[ai][bi] = __builtin_amdgcn_mfma_f32_16x16x32_bf16(
                    af[ai], bf[bi], acc[ai][bi], 0, 0, 0);
    }

    if (z < 2) {
        unsigned short* O = (z == 0) ? Qb : Kb;
        #pragma unroll
        for (int bi = 0; bi < 4; bi++) {
            int token = m0 + wb * 64 + bi * 16 + l15;
            float qs = 1.0f;
            if (z == 0) qs = scal[token >> 11] * 1.44269504f;
            #pragma unroll
            for (int ai = 0; ai < 4; ai++) {
                int feat = n0 + wa * 64 + ai * 16 + quad * 4;
                float v0 = acc[ai][bi][0], v1 = acc[ai][bi][1];
                float v2 = acc[ai][bi][2], v3 = acc[ai][bi][3];
                if (z == 0) { v0 *= qs; v1 *= qs; v2 *= qs; v3 *= qs; }
                uint2 u;
                u.x = pkbf(v0, v1);
                u.y = pkbf(v2, v3);
                *(uint2*)(void*)(O + (size_t)token * DM + feat) = u;
            }
        }
    } else {
        #pragma unroll
        for (int ai = 0; ai < 4; ai++) {
            int token0 = m0 + wa * 64 + ai * 16 + quad * 4;
            int n = token0 >> 11, tl = token0 & 2047;
            #pragma unroll
            for (int bi = 0; bi < 4; bi++) {
                int feat = n0 + wb * 64 + bi * 16 + l15;
                uint2 u;
                u.x = pkbf(acc[ai][bi][0], acc[ai][bi][1]);
                u.y = pkbf(acc[ai][bi][2], acc[ai][bi][3]);
                *(uint2*)(void*)(Vt + ((size_t)n * DM + feat) * LK + tl) = u;
            }
        }
    }
}

// ---------------------------------------------------------------------------
// Flash attention, MAX-FREE + in-register P (permlane).
//
// Round-7 restructure (KVBLK=128): the r3/r5/r6 three-point fit proved
//   wall = wave-iterations x ~1.21ns, with per-iteration cost DOMINATED BY
//   FIXED OVERHEAD (r3->r5: halving per-iter work left cost unchanged).
// So: amortize 128 keys (two 64-key sub-tiles) under ONE barrier+drain.
// Shape: back to r3's best-measured layout (16 blocks/nh, 4 waves, 2 strips
// per wave). Wave-iterations: sum_bx ceil(min(32-bx,tv)/2) ~= 0.51x of r3.
//   - K tile 128x64 staged via 4 GLOAD_LDS, DOUBLE buffered (2x16KB=32KB).
//   - K(kt+1) prefetch issued at the TOP of iter kt (oldest in queue):
//     the whole ~2-sub-tile body covers its HBM/L2 latency.
//   - Single vmcnt(0) at end of body: my prefetch must be LANDED before the
//     next barrier because OTHER waves read it right after.
//   - Raw s_barrier (no implicit full drain), sched_barrier(0) pinned.
// ---------------------------------------------------------------------------
__global__ __launch_bounds__(256) void attn_kernel(
    const unsigned short* __restrict__ Qb, const unsigned short* __restrict__ Kb,
    const unsigned short* __restrict__ Vt,
    const int* __restrict__ valid_arr,
    float* __restrict__ out)
{
    __shared__ unsigned short Kls[2][128 * 64];

    // balanced XCD swizzle: all 4 samples on every XCD; per-XCD K/V set = 4MB
    int id = blockIdx.x;               // 0..1023
    int xcd = id & 7;
    int slot = id >> 3;                // 0..127
    int g = slot >> 4;                 // 0..7: (n, h-parity) group
    int bx = slot & 15;                // strip pair index; bx=0 longest first
    int n = g >> 1;
    int h = 2 * xcd + (g & 1);

    int tA = bx, tB = 31 - bx;

    int valid = valid_arr[n];
    int tvalid = (valid + 63) >> 6;
    int TlA = (tA + 1 < tvalid) ? tA + 1 : tvalid;
    int TlB = (tB + 1 < tvalid) ? tB + 1 : tvalid;
    int Tpair = (TlB + 1) >> 1;        // 128-key iterations (block-uniform)

    int t = threadIdx.x;
    int wave = t >> 6, lane = t & 63;
    int l15 = lane & 15, quad = lane >> 4;

    int qyA = tA * 64 + wave * 16 + l15;
    int qyB = tB * 64 + wave * 16 + l15;
    int qw0A = tA * 64 + wave * 16;
    int qw0B = tB * 64 + wave * 16;

    const unsigned short* QrowA = Qb + ((size_t)n * LQ + qyA) * DM + h * DHEAD;
    const unsigned short* QrowB = Qb + ((size_t)n * LQ + qyB) * DM + h * DHEAD;
    short8 qfA0 = *(const short8*)(const void*)(QrowA + quad * 8);
    short8 qfA1 = *(const short8*)(const void*)(QrowA + 32 + quad * 8);
    short8 qfB0 = *(const short8*)(const void*)(QrowB + quad * 8);
    short8 qfB1 = *(const short8*)(const void*)(QrowB + 32 + quad * 8);

    f32x4 OA[4], OB[4];
    #pragma unroll
    for (int i = 0; i < 4; i++) { OA[i] = zero4(); OB[i] = zero4(); }
    f32x4 LAcc = zero4(), LBcc = zero4();

    short8 onesf;
    #pragma unroll
    for (int i = 0; i < 8; i++) onesf[i] = (short)0x3F80;   // bf16 1.0

    const unsigned short* Kbase = Kb + (size_t)n * LK * DM + h * DHEAD;
    const unsigned short* Vbase = Vt + ((size_t)n * DM + h * DHEAD) * LK;

    // staging: 256 threads cover 32 rows per GLOAD call (8 thr/row x 8 shorts);
    // 4 calls cover the 128-row tile. XOR col-group swizzle on the source.
    int srow0 = t >> 3;
    int sgk   = (((t & 7) ^ (srow0 & 7)) << 3);

    // prologue: stage K tile 0 (rows 0..127) into buf 0
    #pragma unroll
    for (int r = 0; r < 4; r++)
        GLOAD_LDS(Kbase + (size_t)(r * 32 + srow0) * DM + sgk,
                  &Kls[0][0] + r * 2048 + wave * 512);
    asm volatile("s_waitcnt vmcnt(0)" ::: "memory");

    // one 64-key sub-tile for both strips (rowoff = sub-tile base in Kls[cur])
    auto sub_tile = [&](int cur, int j64, int rowoff, bool doA) {
        int jb = j64 << 6;

        // V fragments first (hidden under QK + softmax)
        short8 vf0[4], vf1[4];
        #pragma unroll
        for (int cb = 0; cb < 4; cb++) {
            vf0[cb] = *(const short8*)(const void*)(
                Vbase + (size_t)(cb * 16 + l15) * LK + jb + quad * 8);
            vf1[cb] = *(const short8*)(const void*)(
                Vbase + (size_t)(cb * 16 + l15) * LK + jb + 32 + quad * 8);
        }

        // S^T = K Q^T (Q pre-scaled by s*log2e)
        f32x4 sA[4], sB[4];
        __builtin_amdgcn_s_setprio(1);
        #pragma unroll
        for (int cb = 0; cb < 4; cb++) {
            const unsigned short* krow =
                &Kls[cur][0] + ((rowoff + cb * 16 + l15) << 6);
            short8 kf0 = *(const short8*)(const void*)(krow + ((quad ^ (l15 & 7)) << 3));
            short8 kf1 = *(const short8*)(const void*)(krow + (((4 + quad) ^ (l15 & 7)) << 3));
            f32x4 sb = zero4();
            sb = __builtin_amdgcn_mfma_f32_16x16x32_bf16(kf0, qfB0, sb, 0, 0, 0);
            sb = __builtin_amdgcn_mfma_f32_16x16x32_bf16(kf1, qfB1, sb, 0, 0, 0);
            sB[cb] = sb;
            if (doA) {
                f32x4 sa = zero4();
                sa = __builtin_amdgcn_mfma_f32_16x16x32_bf16(kf0, qfA0, sa, 0, 0, 0);
                sa = __builtin_amdgcn_mfma_f32_16x16x32_bf16(kf1, qfA1, sa, 0, 0, 0);
                sA[cb] = sa;
            }
        }
        __builtin_amdgcn_s_setprio(0);

        // ---- strip B: mask (boundary tiles only), exp2, pack, permlane ----
        if (jb + 63 > qw0B || jb + 64 > valid) {
            #pragma unroll
            for (int cb = 0; cb < 4; cb++) {
                int jb2 = jb + cb * 16 + quad * 4;
                #pragma unroll
                for (int r = 0; r < 4; r++) {
                    int j = jb2 + r;
                    if (j > qyB || j >= valid) sB[cb][r] = -1e30f;
                }
            }
        }
        short8 pfB0, pfB1;
        {
            unsigned int lo[4], hi[4];
            #pragma unroll
            for (int cb = 0; cb < 4; cb++) {
                lo[cb] = pkbf(__builtin_amdgcn_exp2f(sB[cb][0]),
                              __builtin_amdgcn_exp2f(sB[cb][1]));
                hi[cb] = pkbf(__builtin_amdgcn_exp2f(sB[cb][2]),
                              __builtin_amdgcn_exp2f(sB[cb][3]));
            }
            asm("v_permlane32_swap_b32 %0, %1" : "+v"(lo[0]), "+v"(lo[1]));
            asm("v_permlane32_swap_b32 %0, %1" : "+v"(hi[0]), "+v"(hi[1]));
            asm("v_permlane32_swap_b32 %0, %1" : "+v"(lo[2]), "+v"(lo[3]));
            asm("v_permlane32_swap_b32 %0, %1" : "+v"(hi[2]), "+v"(hi[3]));
            asm("v_permlane16_swap_b32 %0, %1" : "+v"(lo[0]), "+v"(lo[1]));
            asm("v_permlane16_swap_b32 %0, %1" : "+v"(hi[0]), "+v"(hi[1]));
            asm("v_permlane16_swap_b32 %0, %1" : "+v"(lo[2]), "+v"(lo[3]));
            asm("v_permlane16_swap_b32 %0, %1" : "+v"(hi[2]), "+v"(hi[3]));
            uint4 w0, w1;
            w0.x = lo[0]; w0.y = hi[0]; w0.z = lo[1]; w0.w = hi[1];
            w1.x = lo[2]; w1.y = hi[2]; w1.z = lo[3]; w1.w = hi[3];
            __builtin_memcpy(&pfB0, &w0, 16);
            __builtin_memcpy(&pfB1, &w1, 16);
        }
        __builtin_amdgcn_s_setprio(1);
        #pragma unroll
        for (int cb = 0; cb < 4; cb++) {
            OB[cb] = __builtin_amdgcn_mfma_f32_16x16x32_bf16(pfB0, vf0[cb], OB[cb], 0, 0, 0);
            OB[cb] = __builtin_amdgcn_mfma_f32_16x16x32_bf16(pfB1, vf1[cb], OB[cb], 0, 0, 0);
        }
        LBcc = __builtin_amdgcn_mfma_f32_16x16x32_bf16(pfB0, onesf, LBcc, 0, 0, 0);
        LBcc = __builtin_amdgcn_mfma_f32_16x16x32_bf16(pfB1, onesf, LBcc, 0, 0, 0);
        __builtin_amdgcn_s_setprio(0);

        // ---- strip A ----
        if (doA) {
            if (jb + 63 > qw0A || jb + 64 > valid) {
                #pragma unroll
                for (int cb = 0; cb < 4; cb++) {
                    int jb2 = jb + cb * 16 + quad * 4;
                    #pragma unroll
                    for (int r = 0; r < 4; r++) {
                        int j = jb2 + r;
                        if (j > qyA || j >= valid) sA[cb][r] = -1e30f;
                    }
                }
            }
            short8 pfA0, pfA1;
            {
                unsigned int lo[4], hi[4];
                #pragma unroll
                for (int cb = 0; cb < 4; cb++) {
                    lo[cb] = pkbf(__builtin_amdgcn_exp2f(sA[cb][0]),
                                  __builtin_amdgcn_exp2f(sA[cb][1]));
                    hi[cb] = pkbf(__builtin_amdgcn_exp2f(sA[cb][2]),
                                  __builtin_amdgcn_exp2f(sA[cb][3]));
                }
                asm("v_permlane32_swap_b32 %0, %1" : "+v"(lo[0]), "+v"(lo[1]));
                asm("v_permlane32_swap_b32 %0, %1" : "+v"(hi[0]), "+v"(hi[1]));
                asm("v_permlane32_swap_b32 %0, %1" : "+v"(lo[2]), "+v"(lo[3]));
                asm("v_permlane32_swap_b32 %0, %1" : "+v"(hi[2]), "+v"(hi[3]));
                asm("v_permlane16_swap_b32 %0, %1" : "+v"(lo[0]), "+v"(lo[1]));
                asm("v_permlane16_swap_b32 %0, %1" : "+v"(hi[0]), "+v"(hi[1]));
                asm("v_permlane16_swap_b32 %0, %1" : "+v"(lo[2]), "+v"(lo[3]));
                asm("v_permlane16_swap_b32 %0, %1" : "+v"(hi[2]), "+v"(hi[3]));
                uint4 w0, w1;
                w0.x = lo[0]; w0.y = hi[0]; w0.z = lo[1]; w0.w = hi[1];
                w1.x = lo[2]; w1.y = hi[2]; w1.z = lo[3]; w1.w = hi[3];
                __builtin_memcpy(&pfA0, &w0, 16);
                __builtin_memcpy(&pfA1, &w1, 16);
            }
            __builtin_amdgcn_s_setprio(1);
            #pragma unroll
            for (int cb = 0; cb < 4; cb++) {
                OA[cb] = __builtin_amdgcn_mfma_f32_16x16x32_bf16(pfA0, vf0[cb], OA[cb], 0, 0, 0);
                OA[cb] = __builtin_amdgcn_mfma_f32_16x16x32_bf16(pfA1, vf1[cb], OA[cb], 0, 0, 0);
            }
            LAcc = __builtin_amdgcn_mfma_f32_16x16x32_bf16(pfA0, onesf, LAcc, 0, 0, 0);
            LAcc = __builtin_amdgcn_mfma_f32_16x16x32_bf16(pfA1, onesf, LAcc, 0, 0, 0);
            __builtin_amdgcn_s_setprio(0);
        }
    };

    int cur = 0;
    for (int kt = 0; kt < Tpair; kt++) {
        __builtin_amdgcn_sched_barrier(0);
        __builtin_amdgcn_s_barrier();          // raw: no implicit full drain
        __builtin_amdgcn_sched_barrier(0);

        // K(kt+1) prefetch FIRST (oldest in queue; whole body covers latency)
        if (kt + 1 < Tpair) {
            size_t rb = (size_t)(kt + 1) << 7;   // 128*(kt+1)
            #pragma unroll
            for (int r = 0; r < 4; r++)
                GLOAD_LDS(Kbase + (rb + r * 32 + srow0) * DM + sgk,
                          &Kls[1 - cur][0] + r * 2048 + wave * 512);
        }

        int j64 = kt << 1;
        sub_tile(cur, j64, 0, j64 < TlA);
        if (j64 + 1 < TlB)
            sub_tile(cur, j64 + 1, 64, j64 + 1 < TlA);

        // my prefetch must be LANDED before the next barrier (other waves
        // read it immediately after). V loads are already retired by PV.
        asm volatile("s_waitcnt vmcnt(0)" ::: "memory");
        cur ^= 1;
    }

    // epilogue (f32): L rows align with O rows (query = quad*4+r) — no shfl.
    float* obase = out + ((size_t)n * LQ) * DM + h * DHEAD;
    #pragma unroll
    for (int r = 0; r < 4; r++) {
        float iA = 1.0f / LAcc[r];
        float iB = 1.0f / LBcc[r];
        int rowA = tA * 64 + wave * 16 + quad * 4 + r;
        int rowB = tB * 64 + wave * 16 + quad * 4 + r;
        #pragma unroll
        for (int cb = 0; cb < 4; cb++) {
            obase[(size_t)rowA * DM + cb * 16 + l15] = OA[cb][r] * iA;
            obase[(size_t)rowB * DM + cb * 16 + l15] = OB[cb][r] * iB;
        }
    }
}

// ---------------------------------------------------------------------------
extern "C" void kernel_launch(void* const* d_in, const int* in_sizes, int n_in,
                              void* d_out, int out_size, void* d_ws, size_t ws_size,
                              hipStream_t stream)
{
    (void)in_sizes; (void)n_in; (void)out_size;

    const float* query = (const float*)d_in[0];
    const float* key   = (const float*)d_in[1];
    const float* Wq    = (const float*)d_in[2];
    const float* Wk    = (const float*)d_in[3];
    const float* Wv    = (const float*)d_in[4];
    const void* pmask  = d_in[6];

    char* ws = (char*)d_ws;
    unsigned short* Qb  = (unsigned short*)(ws);                              // 16 MB
    unsigned short* Kb  = (unsigned short*)(ws + (size_t)16 * 1024 * 1024);   // 16 MB
    unsigned short* Vt  = (unsigned short*)(ws + (size_t)32 * 1024 * 1024);   // 16 MB
    int*   valid = (int*)  (ws + (size_t)48 * 1024 * 1024);
    float* scal  = (float*)(ws + (size_t)48 * 1024 * 1024 + 64);
    unsigned short* Wqb = (unsigned short*)(ws + (size_t)48 * 1024 * 1024 + 4096);
    unsigned short* Wkb = Wqb + (size_t)DM * DM;
    unsigned short* Wvb = Wkb + (size_t)DM * DM;
    unsigned short* XbQ = Wvb + (size_t)DM * DM;     // 16 MB
    unsigned short* XbK = XbQ + (size_t)N_S * LQ * DM;   // 16 MB (full tier only)

    size_t xbytes      = (size_t)N_S * LQ * DM * 2;
    size_t need_phased = (size_t)(48 * 1024 * 1024) + 4096
                       + 3 * (size_t)DM * DM * 2 + xbytes;
    size_t need_full   = need_phased + xbytes;

    if (ws_size >= need_full) {
        // full tier: ONE prep dispatch (meta + convw + convx2), one fused
        // XCD-swizzled projection dispatch, one attention dispatch.
        prep_kernel<<<dim3(1 + 768 + 4096), 256, 0, stream>>>(
            pmask, valid, scal, Wq, Wk, Wv, Wqb, Wkb, Wvb,
            query, key, XbQ, XbK);
        proj_bf16_swz_kernel<<<dim3(1536), 256, 0, stream>>>(
            XbQ, XbK, Wqb, Wkb, Wvb, scal, valid, Qb, Kb, Vt);
    } else if (ws_size >= need_phased) {
        // phased tier: one Xb buffer, reused.
        meta_kernel<<<1, 256, 0, stream>>>(pmask, valid, scal);
        convw_kernel<<<dim3(256, 3), 256, 0, stream>>>(Wq, Wk, Wv, Wqb, Wkb, Wvb);
        convx_kernel<<<2048, 256, 0, stream>>>(query, XbQ);
        proj_bf16_kernel<<<dim3(64, 8, 1), 256, 0, stream>>>(
            XbQ, XbQ, Wqb, Wkb, Wvb, scal, valid, Qb, Kb, Vt, 0);
        convx_kernel<<<2048, 256, 0, stream>>>(key, XbQ);
        proj_bf16_kernel<<<dim3(64, 8, 2), 256, 0, stream>>>(
            XbQ, XbQ, Wqb, Wkb, Wvb, scal, valid, Qb, Kb, Vt, 1);
    } else {
        meta_kernel<<<1, 256, 0, stream>>>(pmask, valid, scal);
        convw_kernel<<<dim3(256, 3), 256, 0, stream>>>(Wq, Wk, Wv, Wqb, Wkb, Wvb);
        proj_f32_kernel<<<dim3(64, 8, 3), 256, 0, stream>>>(
            query, key, Wqb, Wkb, Wvb, scal, Qb, Kb, Vt);
    }

    attn_kernel<<<dim3(1024), 256, 0, stream>>>(Qb, Kb, Vt, valid,
                                                (float*)d_out);
}